// Round 5
// baseline (437.572 us; speedup 1.0000x reference)
//
#include <hip/hip_runtime.h>
#include <hip/hip_bf16.h>

// DCell forward, bf16-MFMA. Round-13:
//  * s4+s3 fusion: act4 (21MB) never materialized. Block (cg,rc) = 8 s4-terms
//    x 64 rows = exactly the children (80 act cols) + genes (64) of 2 s3
//    terms. s4s3_fused: recompute s4 h (MFMA, identical order to stats pass)
//    -> BN+tanh -> act tile in LDS -> s4 head out -> s3 MFMA (A from LDS act
//    + LDS genes, B direct from L2-hot wbt3) -> h3 + 64-chunk col stats.
//    Replaces s4_fused<true> + gemm_small-s3; saves act4 store/load + gene
//    re-read (~59MB) + 1 launch. k in [144,192) contributed exactly 0 before
//    (B zero-padded) -> skipping is bit-exact.
//  * s2 gemm_small BN 64->96, one o-tile (was 2): A-panel staged once (~22MB).
//  * gemm_split/round-8 body stays FROZEN (r9/r10/r11 all regressed).
// Swizzle: id = c + 8*(q*nTiles + n), group = q*8+c = (b-tile*T*KS + t*KS + ks).
// Stage cfg (T,I,O,C,Gs): s4(256,16,20,0,16) s3(64,144,20,80,64)
//  s2(16,336,77,80,256) s1(4,1332,308,308,1024) s0(1,5328,1229,1232,4096)

#define BDIM 2048
#define OUTW 341

typedef __attribute__((ext_vector_type(8))) short short8;
typedef __attribute__((ext_vector_type(4))) float float4v;

static __device__ __forceinline__ unsigned short f2bf(float f) {
    union { float f; unsigned u; } c{f};
    unsigned r = c.u + 0x7FFF + ((c.u >> 16) & 1);  // RNE
    return (unsigned short)(r >> 16);
}
static __device__ __forceinline__ float bf2f(unsigned short s) {
    union { unsigned u; float f; } c{(unsigned)s << 16};
    return c.f;
}

static __device__ __forceinline__ float fast_tanh(float x) {
    float ax = __builtin_fabsf(x);
    float e  = __builtin_amdgcn_exp2f(ax * 2.8853900817779268f);  // e^{2|x|}
    float r  = 1.f - 2.f * __builtin_amdgcn_rcpf(e + 1.f);
    return __builtin_copysignf(r, x);
}

// async global->LDS, 16B/lane: wave-uniform base + lane*16.
static __device__ __forceinline__ void stage16(const void* g, void* ldsBase, int lane) {
#if __has_builtin(__builtin_amdgcn_global_load_lds)
    __builtin_amdgcn_global_load_lds(
        (const __attribute__((address_space(1))) unsigned int*)(uintptr_t)g,
        (__attribute__((address_space(3))) unsigned int*)(unsigned int)(uintptr_t)ldsBase,
        16, 0, 0);
#else
    *(uint4*)((char*)ldsBase + lane * 16) = *(const uint4*)g;
#endif
}

// ---- W[t][I][O] fp32 -> WbT[t][Npad][Kpad] bf16 core ----
static __device__ __forceinline__ void cvt_w_body(const float* Wt, unsigned short* dst,
                                                  int I, int O, int Npad, int Kpad,
                                                  int i0, int o0, int tid) {
    __shared__ unsigned short tile[32][33];
    const int c = tid & 31, r0 = tid >> 5;
    #pragma unroll
    for (int rr = 0; rr < 4; rr++) {
        int i = i0 + r0 + rr * 8, o = o0 + c;
        float v = (i < I && o < O) ? Wt[(size_t)i * O + o] : 0.f;
        tile[r0 + rr * 8][c] = f2bf(v);
    }
    __syncthreads();
    #pragma unroll
    for (int rr = 0; rr < 4; rr++) {
        int o = o0 + r0 + rr * 8, k = i0 + c;
        if (o < Npad) dst[(size_t)o * Kpad + k] = tile[c][r0 + rr * 8];
    }
}

// ---- fused: x pack (read once -> bf16 into ain0/ain1 + zero pads) AND
//      W4..W1 -> bf16 WbT conversion. Disjoint inputs/outputs, no ordering.
#define PACK_BLOCKS ((BDIM * 512 + BDIM * 24 + 255) / 256)   // 4288
__global__ __launch_bounds__(256) void pack_cvt(const float* __restrict__ x,
                                                unsigned short* __restrict__ ain0,
                                                unsigned short* __restrict__ ain1,
                                                const float* __restrict__ W4,
                                                const float* __restrict__ W3,
                                                const float* __restrict__ W2,
                                                const float* __restrict__ W1,
                                                unsigned short* __restrict__ wbt) {
    int bid = blockIdx.x;
    if (bid < PACK_BLOCKS) {
        const int MAIN = BDIM * 512;          // 8-float units
        int i = bid * 256 + threadIdx.x;
        if (i < MAIN) {
            int b = i >> 9, j = i & 511;
            const float* xp = x + (size_t)b * 4096 + j * 8;
            float4 lo = *(const float4*)xp, hi = *(const float4*)(xp + 4);
            union { unsigned short u[8]; uint4 v4; uint2 v2[2]; } t;
            t.u[0] = f2bf(lo.x); t.u[1] = f2bf(lo.y); t.u[2] = f2bf(lo.z); t.u[3] = f2bf(lo.w);
            t.u[4] = f2bf(hi.x); t.u[5] = f2bf(hi.y); t.u[6] = f2bf(hi.z); t.u[7] = f2bf(hi.w);
            *(uint4*)(ain0 + (size_t)b * 5376 + 1232 + j * 8) = t.v4;       // 16B aligned
            int gi = j * 8, tt = gi >> 10, u = gi & 1023;
            unsigned short* d1 = ain1 + (size_t)b * 5376 + tt * 1344 + 308 + u;  // 8B aligned
            *(uint2*)d1 = t.v2[0];
            *(uint2*)(d1 + 4) = t.v2[1];
            return;
        }
        int zi = i - MAIN;                    // zero pads, uint2 (4-short) units
        const int ZU = BDIM * 12;             // per-buffer zero units
        if (zi < ZU) {                        // ain0: cols [5328,5376)
            int b = zi / 12, u = zi % 12;
            *(uint2*)(ain0 + (size_t)b * 5376 + 5328 + u * 4) = make_uint2(0u, 0u);
        } else if (zi < 2 * ZU) {             // ain1: cols [t*1344+1332, +1344)
            zi -= ZU;
            int b = zi / 12, u = zi % 12, tt = u / 3, k = u % 3;
            *(uint2*)(ain1 + (size_t)b * 5376 + tt * 1344 + 1332 + k * 4) = make_uint2(0u, 0u);
        }
        return;
    }
    bid -= PACK_BLOCKS;
    const float* W; unsigned short* dst;
    int I, O, Npad, Kpad, gx, gy, local;
    if (bid < 256)       { W = W4; dst = wbt;           I = 16;   O = 20;  Npad = 20;  Kpad = 32;   gx = 1;  gy = 1;  local = bid; }
    else if (bid < 640)  { W = W3; dst = wbt + 163840;  I = 144;  O = 20;  Npad = 20;  Kpad = 192;  gx = 6;  gy = 1;  local = bid - 256; }
    else if (bid < 1216) { W = W2; dst = wbt + 409600;  I = 336;  O = 77;  Npad = 77;  Kpad = 384;  gx = 12; gy = 3;  local = bid - 640; }
    else                 { W = W1; dst = wbt + 882688;  I = 1332; O = 308; Npad = 320; Kpad = 1344; gx = 42; gy = 10; local = bid - 1216; }
    int per = gx * gy;
    int t = local / per, rem = local % per;
    int by = rem / gx, bx = rem % gx;
    cvt_w_body(W + (size_t)t * I * O, dst + (size_t)t * Npad * Kpad,
               I, O, Npad, Kpad, bx * 32, by * 32, threadIdx.x);
}

__global__ __launch_bounds__(256) void cvt_w(const float* __restrict__ W,
                                             unsigned short* __restrict__ WbT,
                                             int I, int O, int Npad, int Kpad) {
    cvt_w_body(W + (size_t)blockIdx.z * I * O, WbT + (size_t)blockIdx.z * Npad * Kpad,
               I, O, Npad, Kpad, blockIdx.x * 32, blockIdx.y * 32, threadIdx.x);
}

// ---- s4 stats pass: 1024 blocks = 32 col-groups (8 t's) x 32 row-chunks.
// h computed in-register via MFMA on wbt-s4; column stats only -> sp[rc][2][5120].
__global__ __launch_bounds__(256) void s4_stats(
    const unsigned short* __restrict__ xg,   // genes, row stride 5376
    const unsigned short* __restrict__ wbt4, // [256][20][32] bf16
    const float* __restrict__ b4,            // flat [5120]
    float* __restrict__ sp)                  // [32][2][5120]
{
    const int cg = blockIdx.x & 31;
    const int rc = blockIdx.x >> 5;
    const int t0 = cg * 8, b0 = rc * 64;
    const int tid = threadIdx.x;
    const int lane = tid & 63, w = tid >> 6;
    const int l15 = lane & 15, quad = lane >> 4;

    __shared__ __align__(16) unsigned short xs[64][168];

    #pragma unroll
    for (int j = 0; j < 4; j++) {
        int i = tid + j * 256;
        int r = i >> 4, gg = i & 15;
        *(uint4*)&xs[r][gg * 8] =
            *(const uint4*)(xg + (size_t)(b0 + r) * 5376 + t0 * 16 + gg * 8);
    }
    if (tid < 128) {
        int r = tid >> 1, gg = 16 + (tid & 1);
        *(uint4*)&xs[r][gg * 8] = make_uint4(0u, 0u, 0u, 0u);
    }
    __syncthreads();

    float4v acc[2][4][2];
    #pragma unroll
    for (int a = 0; a < 2; a++)
        #pragma unroll
        for (int b = 0; b < 4; b++)
            #pragma unroll
            for (int c = 0; c < 2; c++)
                acc[a][b][c] = (float4v){0.f, 0.f, 0.f, 0.f};

    #pragma unroll
    for (int ti = 0; ti < 2; ti++) {
        const int lt = w * 2 + ti;
        const int t = t0 + lt;
        short8 bf[2];
        #pragma unroll
        for (int nf = 0; nf < 2; nf++)
            bf[nf] = *(const short8*)(wbt4 + ((size_t)t * 20 + nf * 16 + l15) * 32 + quad * 8);
        #pragma unroll
        for (int mf = 0; mf < 4; mf++) {
            short8 a = *(const short8*)&xs[mf * 16 + l15][lt * 16 + quad * 8];
            #pragma unroll
            for (int nf = 0; nf < 2; nf++)
                acc[ti][mf][nf] = __builtin_amdgcn_mfma_f32_16x16x32_bf16(a, bf[nf], acc[ti][mf][nf], 0, 0, 0);
        }
    }

    #pragma unroll
    for (int ti = 0; ti < 2; ti++) {
        const int lt = w * 2 + ti;
        #pragma unroll
        for (int nf = 0; nf < 2; nf++) {
            const int o = nf * 16 + l15;
            const int col = (t0 + lt) * 20 + o;
            const bool valid = (o < 20);
            const float bias = valid ? b4[col] : 0.f;
            float s = 0.f, s2 = 0.f;
            #pragma unroll
            for (int mf = 0; mf < 4; mf++)
                #pragma unroll
                for (int r = 0; r < 4; r++) {
                    float v = acc[ti][mf][nf][r] + bias;
                    s += v; s2 += v * v;
                }
            s  += __shfl_xor(s, 16, 64);  s  += __shfl_xor(s, 32, 64);
            s2 += __shfl_xor(s2, 16, 64); s2 += __shfl_xor(s2, 32, 64);
            if (quad == 0 && valid) {
                sp[(size_t)rc * 10240 + col] = s;
                sp[(size_t)rc * 10240 + 5120 + col] = s2;
            }
        }
    }
}

// ---- s4+s3 fused: recompute s4 h -> BN+tanh -> act tile in LDS -> s4 head
// -> s3 MFMA (A: LDS act[80] + LDS genes[64]; B: global wbt3, L2-hot)
// -> h3 + 64-chunk column stats. act4 never touches HBM.
// Block (cg,rc): s4 terms [cg*8,+8), s3 terms [cg*2,+2), rows [rc*64,+64).
__global__ __launch_bounds__(256) void s4s3_fused(
    const unsigned short* __restrict__ xg,   // genes, row stride 5376
    const unsigned short* __restrict__ wbt4, // [256][20][32]
    const unsigned short* __restrict__ wbt3, // [64][20][192]
    const float* __restrict__ b4,            // [5120]
    const float* __restrict__ ss,            // [2][5120] s4 scale/shift
    const float* __restrict__ hw4,           // [5120]
    const float* __restrict__ hb4,           // [256]
    const float* __restrict__ b3,            // [1280]
    unsigned short* __restrict__ h3,         // [2048][1280]
    float* __restrict__ sp3,                 // [64][2][1280]
    float* __restrict__ out)
{
    const int cg = blockIdx.x & 31;
    const int rc = blockIdx.x >> 5;
    const int t0 = cg * 8, b0 = rc * 64;
    const int tid = threadIdx.x;
    const int lane = tid & 63, w = tid >> 6;
    const int l15 = lane & 15, quad = lane >> 4;

    // gs: 128 genes + zero [128,144) + pad (152*2B = 16B-mult, 2-way banks)
    __shared__ __align__(16) unsigned short gs[64][152];
    // as_: act tile, col = lt*20+o (168*2B = 16B-mult, 2-way banks)
    __shared__ __align__(16) unsigned short as_[64][168];

    #pragma unroll
    for (int j = 0; j < 4; j++) {
        int i = tid + j * 256;
        int r = i >> 4, gg = i & 15;
        *(uint4*)&gs[r][gg * 8] =
            *(const uint4*)(xg + (size_t)(b0 + r) * 5376 + t0 * 16 + gg * 8);
    }
    if (tid < 128) {
        int r = tid >> 1, gg = 16 + (tid & 1);
        *(uint4*)&gs[r][gg * 8] = make_uint4(0u, 0u, 0u, 0u);
    }
    __syncthreads();

    // ---- phase 1: s4 MFMA (identical order to s4_stats -> stats consistent)
    float4v acc4[2][4][2];
    #pragma unroll
    for (int a = 0; a < 2; a++)
        #pragma unroll
        for (int b = 0; b < 4; b++)
            #pragma unroll
            for (int c = 0; c < 2; c++)
                acc4[a][b][c] = (float4v){0.f, 0.f, 0.f, 0.f};

    #pragma unroll
    for (int ti = 0; ti < 2; ti++) {
        const int lt = w * 2 + ti;
        const int t = t0 + lt;
        short8 bf[2];
        #pragma unroll
        for (int nf = 0; nf < 2; nf++)
            bf[nf] = *(const short8*)(wbt4 + ((size_t)t * 20 + nf * 16 + l15) * 32 + quad * 8);
        #pragma unroll
        for (int mf = 0; mf < 4; mf++) {
            short8 a = *(const short8*)&gs[mf * 16 + l15][lt * 16 + quad * 8];
            #pragma unroll
            for (int nf = 0; nf < 2; nf++)
                acc4[ti][mf][nf] = __builtin_amdgcn_mfma_f32_16x16x32_bf16(a, bf[nf], acc4[ti][mf][nf], 0, 0, 0);
        }
    }

    // ---- phase 2: BN+tanh -> act into as_ (LDS) + s4 head -> out
    #pragma unroll
    for (int ti = 0; ti < 2; ti++) {
        const int lt = w * 2 + ti;
        const int t4 = t0 + lt;
        float hp[4][4];
        #pragma unroll
        for (int mf = 0; mf < 4; mf++)
            #pragma unroll
            for (int r = 0; r < 4; r++) hp[mf][r] = 0.f;
        #pragma unroll
        for (int nf = 0; nf < 2; nf++) {
            const int o = nf * 16 + l15;
            const int col = t4 * 20 + o;
            const bool valid = (o < 20);
            const float scale = valid ? ss[col] : 0.f;
            const float shp   = valid ? (b4[col] * scale + ss[5120 + col]) : 0.f;
            const float hwv   = valid ? hw4[col] : 0.f;
            #pragma unroll
            for (int mf = 0; mf < 4; mf++)
                #pragma unroll
                for (int r = 0; r < 4; r++) {
                    float av = fast_tanh(acc4[ti][mf][nf][r] * scale + shp);
                    if (valid)
                        as_[mf * 16 + quad * 4 + r][lt * 20 + o] = f2bf(av);
                    hp[mf][r] += av * hwv;
                }
        }
        const float hbv = hb4[t4];
        #pragma unroll
        for (int mf = 0; mf < 4; mf++)
            #pragma unroll
            for (int r = 0; r < 4; r++) {
                float v = hp[mf][r];
                v += __shfl_xor(v, 1, 64); v += __shfl_xor(v, 2, 64);
                v += __shfl_xor(v, 4, 64); v += __shfl_xor(v, 8, 64);
                if (l15 == 0)
                    out[(size_t)(b0 + mf * 16 + quad * 4 + r) * OUTW + t4] = v + hbv;
            }
    }
    __syncthreads();   // as_ fully written before s3 reads

    // ---- phase 3: s3 MFMA. wave: t = cg*2 + (w&1), m-half = w>>1.
    // A k-layout: k<80 act (as_ cols t3l*80+k), k in [80,160) genes
    // (gs cols t3l*64 + k-80; [128,152) region finite, B zero there).
    const int t3l = w & 1, mh = w >> 1;
    const int t3 = cg * 2 + t3l;
    float4v acc3[2][2];
    #pragma unroll
    for (int a = 0; a < 2; a++)
        #pragma unroll
        for (int b = 0; b < 2; b++)
            acc3[a][b] = (float4v){0.f, 0.f, 0.f, 0.f};

    #pragma unroll
    for (int ks = 0; ks < 5; ks++) {
        const int k = ks * 32 + quad * 8;
        short8 bf[2];
        #pragma unroll
        for (int nf = 0; nf < 2; nf++)
            bf[nf] = *(const short8*)(wbt3 + ((size_t)t3 * 20 + nf * 16 + l15) * 192 + ks * 32 + quad * 8);
        #pragma unroll
        for (int mf2 = 0; mf2 < 2; mf2++) {
            const int row = (mh * 2 + mf2) * 16 + l15;
            const unsigned short* ap = (k < 80) ? &as_[row][t3l * 80 + k]
                                                : &gs[row][t3l * 64 + (k - 80)];
            short8 a = *(const short8*)ap;
            #pragma unroll
            for (int nf = 0; nf < 2; nf++)
                acc3[mf2][nf] = __builtin_amdgcn_mfma_f32_16x16x32_bf16(a, bf[nf], acc3[mf2][nf], 0, 0, 0);
        }
    }

    // ---- phase 4: h3 + per-32-row-chunk column stats (chunk = rc*2+mh)
    float ss_[2], ss2_[2];
    #pragma unroll
    for (int nf = 0; nf < 2; nf++) { ss_[nf] = 0.f; ss2_[nf] = 0.f; }
    #pragma unroll
    for (int mf2 = 0; mf2 < 2; mf2++)
        #pragma unroll
        for (int nf = 0; nf < 2; nf++) {
            const int o = nf * 16 + l15;
            const int col = t3 * 20 + o;
            const bool valid = (o < 20);
            const float bias = valid ? b3[col] : 0.f;
            #pragma unroll
            for (int r = 0; r < 4; r++) {
                const int m = (mh * 2 + mf2) * 16 + quad * 4 + r;
                float v = acc3[mf2][nf][r] + bias;
                if (valid)
                    h3[(size_t)(b0 + m) * 1280 + col] = f2bf(v);
                ss_[nf] += v; ss2_[nf] += v * v;
            }
        }
    #pragma unroll
    for (int nf = 0; nf < 2; nf++) {
        ss_[nf]  += __shfl_xor(ss_[nf], 16, 64);  ss_[nf]  += __shfl_xor(ss_[nf], 32, 64);
        ss2_[nf] += __shfl_xor(ss2_[nf], 16, 64); ss2_[nf] += __shfl_xor(ss2_[nf], 32, 64);
        const int o = nf * 16 + l15;
        if (quad == 0 && o < 20) {
            const int col = t3 * 20 + o;
            const size_t base = (size_t)(rc * 2 + mh) * 2560;
            sp3[base + col] = ss_[nf];
            sp3[base + 1280 + col] = ss2_[nf];
        }
    }
}

// ---- small-stage GEMM + fused column stats (chunk = blockIdx.y, 32 chunks of 64 rows)
template <int BN, int BK>
__global__ __launch_bounds__(256) void gemm_small(
    const unsigned short* __restrict__ actb,  // [B][T*C] bf16 (null if C==0)
    const unsigned short* __restrict__ xg,    // bf16 x copy, row stride 5376
    const unsigned short* __restrict__ WbT,   // [T][O][Kpad] bf16
    const float* __restrict__ bias,
    unsigned short* __restrict__ h,           // [B][hstride]
    float* __restrict__ sp,                   // [32][2*TO] col-sum partials
    int T, int I, int O, int C, int Gs, int Kpad, int hstride, int TO)
{
    const int t  = blockIdx.z;
    const int b0 = blockIdx.y * 64;
    const int o0 = blockIdx.x * BN;
    const int tid = threadIdx.x;
    const int lane = tid & 63;
    const int w = tid >> 6;
    const int l15 = lane & 15;
    const int quad = lane >> 4;

    constexpr int NF = BN / 32;
    const int wm = (w & 1) * 32;
    const int wn = (w >> 1) * (BN / 2);

    __shared__ __align__(16) unsigned short As[64][BK + 8];
    __shared__ __align__(16) unsigned short Bs[BN][BK + 8];
    __shared__ float ldsS[2][BN], ldsS2[2][BN];

    float4v acc[2][NF];
    #pragma unroll
    for (int a = 0; a < 2; a++)
        #pragma unroll
        for (int b = 0; b < NF; b++)
            acc[a][b] = (float4v){0.f, 0.f, 0.f, 0.f};

    constexpr int GR = BK / 8;
    constexpr int AG = 64 * GR;
    constexpr int BG = BN * GR;
    const size_t actRow = (size_t)T * C;

    for (int k0 = 0; k0 < Kpad; k0 += BK) {
        #pragma unroll
        for (int g = tid; g < AG; g += 256) {
            const int r = g / GR, c8 = g % GR;
            const int k = k0 + c8 * 8;
            const int b = b0 + r;
            uint4 v;
            if (k + 8 <= C) {
                v = *(const uint4*)(actb + (size_t)b * actRow + (size_t)t * C + k);
            } else if (k >= I) {
                v = make_uint4(0u, 0u, 0u, 0u);
            } else {
                v = *(const uint4*)(xg + (size_t)b * 5376 + (size_t)t * Gs + (k - C));
            }
            *(uint4*)&As[r][c8 * 8] = v;
        }
        #pragma unroll
        for (int g = tid; g < BG; g += 256) {
            const int n = g / GR, c8 = g % GR;
            const int o = o0 + n;
            uint4 v = make_uint4(0u, 0u, 0u, 0u);
            if (o < O)
                v = *(const uint4*)(WbT + ((size_t)t * O + o) * Kpad + k0 + c8 * 8);
            *(uint4*)&Bs[n][c8 * 8] = v;
        }
        __syncthreads();
        #pragma unroll
        for (int ks = 0; ks < BK / 32; ks++) {
            const int koff = ks * 32 + quad * 8;
            short8 a0 = *(const short8*)&As[wm + l15][koff];
            short8 a1 = *(const short8*)&As[wm + 16 + l15][koff];
            #pragma unroll
            for (int fn = 0; fn < NF; fn++) {
                short8 bf = *(const short8*)&Bs[wn + fn * 16 + l15][koff];
                acc[0][fn] = __builtin_amdgcn_mfma_f32_16x16x32_bf16(a0, bf, acc[0][fn], 0, 0, 0);
                acc[1][fn] = __builtin_amdgcn_mfma_f32_16x16x32_bf16(a1, bf, acc[1][fn], 0, 0, 0);
            }
        }
        __syncthreads();
    }

    // epilogue + per-thread column partial sums (fp32, pre-rounding)
    float csum[NF], csum2[NF];
    #pragma unroll
    for (int fn = 0; fn < NF; fn++) { csum[fn] = 0.f; csum2[fn] = 0.f; }
    #pragma unroll
    for (int fm = 0; fm < 2; fm++)
        #pragma unroll
        for (int fn = 0; fn < NF; fn++)
            #pragma unroll
            for (int r = 0; r < 4; r++) {
                int m = wm + fm * 16 + quad * 4 + r;
                int o = o0 + wn + fn * 16 + l15;
                if (o < O) {
                    float v = acc[fm][fn][r] + bias[t * O + o];
                    h[(size_t)(b0 + m) * hstride + (size_t)t * O + o] = f2bf(v);
                    csum[fn] += v; csum2[fn] += v * v;
                }
            }
    #pragma unroll
    for (int fn = 0; fn < NF; fn++) {
        csum[fn]  += __shfl_xor(csum[fn], 16, 64);
        csum[fn]  += __shfl_xor(csum[fn], 32, 64);
        csum2[fn] += __shfl_xor(csum2[fn], 16, 64);
        csum2[fn] += __shfl_xor(csum2[fn], 32, 64);
    }
    if (quad == 0) {
        #pragma unroll
        for (int fn = 0; fn < NF; fn++) {
            ldsS[w & 1][wn + fn * 16 + l15]  = csum[fn];
            ldsS2[w & 1][wn + fn * 16 + l15] = csum2[fn];
        }
    }
    __syncthreads();
    if (tid < BN && o0 + tid < O) {
        int col = t * O + o0 + tid;
        size_t base = (size_t)blockIdx.y * 2 * TO;
        sp[base + col]      = ldsS[0][tid] + ldsS[1][tid];
        sp[base + TO + col] = ldsS2[0][tid] + ldsS2[1][tid];
    }
}

// ---- big-stage GEMM (s1/s0): 128-row tile, BK=32, dbuf LDS, XCD-swizzled 1D grid
// (round-8 proven body, frozen).
template <int BN>
__global__ __launch_bounds__(256) void gemm_split(
    const unsigned short* __restrict__ A,     // [2048][aStride] bf16 (zero-padded)
    const unsigned short* __restrict__ WbT,   // [T][Npad][Kpad] bf16 (zero-padded)
    float* __restrict__ partial,              // [KS][2048][TNpad]
    int aStride, int tStride, int Kpad, int Npad, int KS, int TNpad,
    int nTiles, int TKS)
{
    const int tid = threadIdx.x;
    const int lane = tid & 63, w = tid >> 6;
    const int l15 = lane & 15, quad = lane >> 4;

    // swizzled decode
    const int id = blockIdx.x;
    const int c = id & 7;
    const int tmp = id >> 3;
    const int n = tmp % nTiles;
    const int q = tmp / nTiles;
    const int group = q * 8 + c;
    const int b0 = (group / TKS) * 128;
    const int rem = group % TKS;
    const int t = rem / KS;
    const int ksIdx = rem - t * KS;
    const int n0 = n * BN;

    __shared__ __align__(16) unsigned short As[2][128 * 32];   // 2 x 8 KB
    __shared__ __align__(16) unsigned short Bs[2][BN * 32];    // 2 x 8/4 KB

    const int S = Kpad >> 5;
    const int qb = S / KS, rb = S % KS;
    const int beg = ksIdx * qb + (ksIdx < rb ? ksIdx : rb);
    const int cnt = qb + (ksIdx < rb ? 1 : 0);

    constexpr int NF = BN / 32;
    const int wm = (w & 1) * 64;
    const int wn = (w >> 1) * (BN / 2);

    float4v acc[4][NF];
    #pragma unroll
    for (int a = 0; a < 4; a++)
        #pragma unroll
        for (int b = 0; b < NF; b++)
            acc[a][b] = (float4v){0.f, 0.f, 0.f, 0.f};

    // A staging: 512 granule-slots, 2 calls/wave
    const unsigned short* aSrc[2];
    int aOff[2];
    #pragma unroll
    for (int j = 0; j < 2; j++) {
        int s = (w * 2 + j) * 64 + lane;
        int r = s >> 2, kg = (s & 3) ^ ((r >> 1) & 3);
        aSrc[j] = A + (size_t)(b0 + r) * aStride + (size_t)t * tStride + kg * 8;
        aOff[j] = (w * 2 + j) * 512;           // shorts
    }
    // B staging
    constexpr int BCALLS = (BN == 128) ? 2 : 1;
    const unsigned short* bSrc[BCALLS];
    int bOff[BCALLS];
    #pragma unroll
    for (int j = 0; j < BCALLS; j++) {
        int s = (w * BCALLS + j) * 64 + lane;
        int r = s >> 2, kg = (s & 3) ^ ((r >> 1) & 3);
        bSrc[j] = WbT + ((size_t)t * Npad + n0 + r) * Kpad + kg * 8;
        bOff[j] = (w * BCALLS + j) * 512;
    }

    // prologue: stage step 0 into buf 0
    {
        const int k0 = beg << 5;
        #pragma unroll
        for (int j = 0; j < 2; j++)      stage16(aSrc[j] + k0, &As[0][aOff[j]], lane);
        #pragma unroll
        for (int j = 0; j < BCALLS; j++) stage16(bSrc[j] + k0, &Bs[0][bOff[j]], lane);
    }

    for (int s = 0; s < cnt; s++) {
        const int cur = s & 1;
        __syncthreads();   // drains cur-buf loads (in flight since prev iter) + prev compute
        if (s + 1 < cnt) {
            const int k1 = (beg + s + 1) << 5;
            #pragma unroll
            for (int j = 0; j < 2; j++)      stage16(aSrc[j] + k1, &As[cur ^ 1][aOff[j]], lane);
            #pragma unroll
            for (int j = 0; j < BCALLS; j++) stage16(bSrc[j] + k1, &Bs[cur ^ 1][bOff[j]], lane);
        }
        short8 af[4];
        #pragma unroll
        for (int fm = 0; fm < 4; fm++) {
            int m = wm + fm * 16 + l15;
            int pos = quad ^ ((m >> 1) & 3);
            af[fm] = *(const short8*)&As[cur][(m * 4 + pos) * 8];
        }
        short8 bfr[NF];
        #pragma unroll
        for (int fn = 0; fn < NF; fn++) {
            int nn = wn + fn * 16 + l15;
            int pos = quad ^ ((nn >> 1) & 3);
            bfr[fn] = *(const short8*)&Bs[cur][(nn * 4 + pos) * 8];
        }
        #pragma unroll
        for (int fm = 0; fm < 4; fm++)
            #pragma unroll
            for (int fn = 0; fn < NF; fn++)
                acc[fm][fn] = __builtin_amdgcn_mfma_f32_16x16x32_bf16(af[fm], bfr[fn], acc[fm][fn], 0, 0, 0);
    }

    const size_t pBase = ((size_t)ksIdx * BDIM + b0) * TNpad + (size_t)t * Npad + n0;
    #pragma unroll
    for (int fm = 0; fm < 4; fm++)
        #pragma unroll
        for (int r = 0; r < 4; r++) {
            const int m = wm + fm * 16 + quad * 4 + r;
            float* prow = partial + pBase + (size_t)m * TNpad + wn;
            #pragma unroll
            for (int fn = 0; fn < NF; fn++)
                prow[fn * 16 + l15] = acc[fm][fn][r];
        }
}

// ---- fused split-K reduce + bias + bf16 h store + per-chunk stats partials ----
__global__ __launch_bounds__(256) void reduce_bias_stats(
    const float* __restrict__ partial, const float* __restrict__ bias,
    unsigned short* __restrict__ h, float* __restrict__ sp,
    int T, int O, int Npad, int KS, int hstride, int TO)
{
    __shared__ float redS[4][64], redS2[4][64];
    const int colL = threadIdx.x & 63;
    const int cr = threadIdx.x >> 6;
    const int col = blockIdx.x * 64 + colL;
    const int chunk = blockIdx.y;
    float s = 0.f, s2 = 0.f;
    if (col < TO) {
        int t = col / O, o = col - t * O;
        const size_t TNpad = (size_t)T * Npad;
        const size_t pcol = (size_t)t * Npad + o;
        const float bv = bias[col];
        const int row0 = chunk * 128 + cr * 32;
        for (int r = 0; r < 32; r++) {
            const int row = row0 + r;
            const float* p = partial + (size_t)row * TNpad + pcol;
            float v = bv;
            for (int ks = 0; ks < KS; ks++) v += p[(size_t)ks * BDIM * TNpad];
            h[(size_t)row * hstride + col] = f2bf(v);
            s += v; s2 += v * v;
        }
    }
    redS[cr][colL] = s; redS2[cr][colL] = s2;
    __syncthreads();
    if (cr == 0 && col < TO) {
        float ts  = redS[0][colL] + redS[1][colL] + redS[2][colL] + redS[3][colL];
        float ts2 = redS2[0][colL] + redS2[1][colL] + redS2[2][colL] + redS2[3][colL];
        sp[(size_t)chunk * 2 * TO + col] = ts;
        sp[(size_t)chunk * 2 * TO + TO + col] = ts2;
    }
}

// ---- fold NC chunk partials -> per-col scale/shift ----
__global__ __launch_bounds__(256) void bn_scaleN(const float* __restrict__ sp,
                                                 const float* __restrict__ g,
                                                 const float* __restrict__ bb,
                                                 float* __restrict__ ss, int TO, int NC) {
    int col = blockIdx.x * 256 + threadIdx.x;
    if (col >= TO) return;
    float s = 0.f, s2 = 0.f;
    for (int c = 0; c < NC; c++) {
        s  += sp[(size_t)c * 2 * TO + col];
        s2 += sp[(size_t)c * 2 * TO + TO + col];
    }
    float mu = s * (1.f / BDIM);
    float var = s2 * (1.f / BDIM) - mu * mu;  // biased, matches jnp.var
    float scale = rsqrtf(var + 1e-5f) * g[col];
    ss[col] = scale;
    ss[TO + col] = bb[col] - mu * scale;
}

// ---- vectorized BN+tanh+head for O=20 in-place stages (s3) ----
template <int GPT>
__global__ __launch_bounds__(256) void bn_tanh_head_vec(
    unsigned short* hact, const float* __restrict__ ss,
    const float* __restrict__ hw, const float* __restrict__ hb,
    float* __restrict__ out,
    int T, int rowGran, int RPB, int hstride, int head_off)
{
    __shared__ float headAcc[256];
    const int tid = threadIdx.x;
    headAcc[tid] = 0.f;
    __syncthreads();
    const int b0 = blockIdx.x * RPB;

    uint2 hv[GPT];
    #pragma unroll
    for (int j = 0; j < GPT; j++) {
        int G = tid + j * 256;
        int r = G / rowGran, gg = G % rowGran;
        hv[j] = *(const uint2*)(hact + (size_t)(b0 + r) * hstride + gg * 4);
    }
    #pragma unroll
    for (int j = 0; j < GPT; j++) {
        int G = tid + j * 256;
        int r = G / rowGran, gg = G % rowGran;
        int c = gg * 4;
        float4 sc = *(const float4*)(ss + c);
        float4 sh = *(const float4*)(ss + hstride + c);
        float4 w4 = *(const float4*)(hw + c);
        union { unsigned short u[4]; uint2 v; } iv, ov;
        iv.v = hv[j];
        float a0 = fast_tanh(bf2f(iv.u[0]) * sc.x + sh.x);
        float a1 = fast_tanh(bf2f(iv.u[1]) * sc.y + sh.y);
        float a2 = fast_tanh(bf2f(iv.u[2]) * sc.z + sh.z);
        float a3 = fast_tanh(bf2f(iv.u[3]) * sc.w + sh.w);
        ov.u[0] = f2bf(a0); ov.u[1] = f2bf(a1); ov.u[2] = f2bf(a2); ov.u[3] = f2bf(a3);
        *(uint2*)(hact + (size_t)(b0 + r) * hstride + c) = ov.v;
        float partial = a0 * w4.x + a1 * w4.y + a2 * w4.z + a3 * w4.w;
        int t = gg / 5;
        atomicAdd(&headAcc[r * T + t], partial);
    }
    __syncthreads();
    if (tid < RPB * T) {
        int r = tid / T, t = tid % T;
        out[(size_t)(b0 + r) * OUTW + head_off + t] = headAcc[tid] + hb[t];
    }
}

// ---- BN + tanh + strided act store + head — WAVE variant ----
__global__ __launch_bounds__(256) void bn_tanh_head(
    const unsigned short* __restrict__ h, const float* __restrict__ ss,
    const float* __restrict__ hw, const float* __restrict__ hb,
    unsigned short* __restrict__ actOut, float* __restrict__ out,
    int T, int O, int hstride, int aRow, int GT, int GS, int head_off, int TO)
{
    int wid  = (blockIdx.x * 256 + threadIdx.x) >> 6;
    int lane = threadIdx.x & 63;
    int b = wid / T;
    int t = wid % T;
    const size_t hbase = (size_t)b * hstride + (size_t)t * O;
    const size_t abase = (size_t)b * aRow + (size_t)(t / GT) * GS + (size_t)(t % GT) * O;
    float hsum = 0.f;
    for (int o = lane; o < O; o += 64) {
        int col = t * O + o;
        float a = fast_tanh(bf2f(h[hbase + o]) * ss[col] + ss[TO + col]);
        if (actOut) actOut[abase + o] = f2bf(a);
        hsum += a * hw[col];
    }
    #pragma unroll
    for (int off = 32; off > 0; off >>= 1) hsum += __shfl_down(hsum, off, 64);
    if (lane == 0) out[(size_t)b * OUTW + head_off + t] = hsum + hb[t];
}

extern "C" void kernel_launch(void* const* d_in, const int* in_sizes, int n_in,
                              void* d_out, int out_size, void* d_ws, size_t ws_size,
                              hipStream_t stream)
{
    const float* x = (const float*)d_in[0];
    float* out = (float*)d_out;
    char* ws = (char*)d_ws;

    // ws layout (bytes)
    unsigned short* wbt  = (unsigned short*)(ws);              // 13,762,560
    unsigned short* ain0 = (unsigned short*)(ws + 13762560);   // 22,020,096 (2048x5376)
    unsigned short* bufA = (unsigned short*)(ws + 35782656);   // 20,971,520 (now unused)
    unsigned short* bufB = (unsigned short*)(ws + 56754176);   //  5,242,880
    unsigned short* ain1 = (unsigned short*)(ws + 61997056);   // 22,020,096
    unsigned short* bufC = (unsigned short*)(ws + 84017152);   //  5,046,272
    float*          ss   = (float*)(ws + 89063424);            //     40,960
    float*          sp0  = (float*)(ws + 89104384);            //    157,312 (16x2x1229)
    // overlays (all verified dead at use time):
    float* partial = (float*)(ws + 35782656);   // s1: 21 MB (=bufA), s0: 41.9 MB (bufA..ain1 head)
    float* sp4 = (float*)bufC;                  // 32x2x5120x4 = 1.31 MB (bufC free pre-s2)
    float* sp3 = (float*)bufC;                  // 64x2x1280x4 = 0.66 MB (sp4 dead post-scaleN)
    float* sp2 = (float*)bufA;                  // 0.32 MB (bufA unused)
    float* sp1 = (float*)bufB;                  // 0.32 MB (act3 dead after s2 gemm)
    unsigned short* xg = ain0 + 1232;           // full bf16 x copy, row stride 5376

    const float* W4 = (const float*)d_in[1];  const float* b4 = (const float*)d_in[2];
    const float* g4 = (const float*)d_in[3];  const float* bb4 = (const float*)d_in[4];
    const float* hw4 = (const float*)d_in[5]; const float* hb4 = (const float*)d_in[6];
    const float* W3 = (const float*)d_in[7];  const float* b3 = (const float*)d_in[8];
    const float* g3 = (const float*)d_in[9];  const float* bb3 = (const float*)d_in[10];
    const float* hw3 = (const float*)d_in[11]; const float* hb3 = (const float*)d_in[12];
    const float* W2 = (const float*)d_in[13]; const float* b2 = (const float*)d_in[14];
    const float* g2 = (const float*)d_in[15]; const float* bb2 = (const float*)d_in[16];
    const float* hw2 = (const float*)d_in[17]; const float* hb2 = (const float*)d_in[18];
    const float* W1 = (const float*)d_in[19]; const float* b1 = (const float*)d_in[20];
    const float* g1 = (const float*)d_in[21]; const float* bb1 = (const float*)d_in[22];
    const float* hw1 = (const float*)d_in[23]; const float* hb1 = (const float*)d_in[24];
    const float* W0 = (const float*)d_in[25]; const float* b0_ = (const float*)d_in[26];
    const float* g0 = (const float*)d_in[27]; const float* bb0 = (const float*)d_in[28];
    const float* hw0 = (const float*)d_in[29]; const float* hb0 = (const float*)d_in[30];

    // 1: fused x pack + weight conversions (s4..s1)
    pack_cvt<<<PACK_BLOCKS + 2896, 256, 0, stream>>>(x, ain0, ain1, W4, W3, W2, W1, wbt);

    // s4 stats: in-register MFMA h -> column stats only
    s4_stats<<<1024, 256, 0, stream>>>(xg, wbt, b4, sp4);
    bn_scaleN<<<20, 256, 0, stream>>>(sp4, g4, bb4, ss, 5120, 32);
    // s4 act recompute + s3 GEMM fused: h3 -> bufB, stats -> sp3 (64 chunks)
    s4s3_fused<<<1024, 256, 0, stream>>>(xg, wbt, wbt + 163840, b4, ss, hw4, hb4,
                                         b3, bufB, sp3, out);

    // s3 BN+tanh+head (act3 in-place in bufB)
    bn_scaleN<<<5, 256, 0, stream>>>(sp3, g3, bb3, ss, 1280, 64);
    bn_tanh_head_vec<5><<<BDIM / 4, 256, 0, stream>>>(bufB, ss, hw3, hb3, out, 64, 320, 4, 1280, 256);

    // s2: T=16 I=336 O=77 Kpad=384, WbT @409600 — BN=96, single o-tile
    gemm_small<96, 64><<<dim3(1, 32, 16), 256, 0, stream>>>(bufB, xg, wbt + 409600, b2, bufC,
                                                            sp2, 16, 336, 77, 80, 256, 384, 1232, 1232);
    bn_scaleN<<<5, 256, 0, stream>>>(sp2, g2, bb2, ss, 1232, 32);
    bn_tanh_head<<<BDIM * 16 / 4, 256, 0, stream>>>(bufC, ss, hw2, hb2,
                                                    ain1, out, 16, 77, 1232, 5376, 4, 1344, 320, 1232);

    // s1: T=4 I=1332 O=308 Kpad=1344 Npad=320 KS=2, WbT @882688
    // swizzled 1D grid: nTiles=5, TKS=T*KS=8, blocks = 5*16*8 = 640
    gemm_split<64><<<640, 256, 0, stream>>>(ain1, wbt + 882688, partial,
                                            5376, 1344, 1344, 320, 2, 1280, 5, 8);
    cvt_w<<<dim3(168, 40, 1), 256, 0, stream>>>(W0, wbt, 5328, 1229, 1280, 5376);  // overlaps s1 tail
    reduce_bias_stats<<<dim3(20, 16), 256, 0, stream>>>(partial, b1, bufC, sp1,
                                                        4, 308, 320, 2, 1232, 1232);
    bn_scaleN<<<5, 256, 0, stream>>>(sp1, g1, bb1, ss, 1232, 16);
    bn_tanh_head<<<BDIM * 4 / 4, 256, 0, stream>>>(bufC, ss, hw1, hb1,
                                                   ain0, out, 4, 308, 1232, 5376, 4, 0, 336, 1232);

    // s0: T=1 I=5328 O=1229 Kpad=5376 Npad=1280 KS=4
    // swizzled 1D grid: nTiles=10, TKS=4, blocks = 10*16*4 = 640
    gemm_split<128><<<640, 256, 0, stream>>>(ain0, wbt, partial,
                                             5376, 0, 5376, 1280, 4, 1280, 10, 4);
    reduce_bias_stats<<<dim3(20, 16), 256, 0, stream>>>(partial, b0_, bufC, sp0,
                                                        1, 1229, 1280, 4, 1232, 1229);
    bn_scaleN<<<5, 256, 0, stream>>>(sp0, g0, bb0, ss, 1229, 16);
    bn_tanh_head<<<BDIM / 4, 256, 0, stream>>>(bufC, ss, hw0, hb0,
                                               nullptr, out, 1, 1229, 1232, 1232, 1, 0, 340, 1229);
}

// Round 6
// 394.372 us; speedup vs baseline: 1.1095x; 1.1095x over previous
//
#include <hip/hip_runtime.h>
#include <hip/hip_bf16.h>

// DCell forward, bf16-MFMA. Round-14:
//  * All 5 bn_scaleN launches ELIMINATED. Producers atomicAdd block-reduced
//    (sum, sumsq) per column into global fp32 accumulators (device-scope HW
//    atomics, NO fences -- r10's poison was __threadfence=L2-writeback, not
//    atomics). Consumers (strictly later in stream) compute scale/shift per
//    column inline (rsqrt + ~10 VALU, single consumer per stage). acc arrays
//    zeroed in pack_cvt (dispatch #1). 19 -> 13 dispatches/iter.
//    Rationale: r12 (-26MB -> -13.5us) + r13 (-59MB -> 0us) falsified the
//    BW model for the tail; pipeline runs at ~1TB/s effective => ~180us is
//    inter-dispatch overhead. This round attacks dispatch count.
//  * W0 cvt split: rows o>=512 write wbt bytes free from t=0 (wbt1 ends at
//    short 2,603,008 < 512*5376) -> converted inside pack_cvt; only rows
//    [0,512) remain in the serial post-s1 slot (cvt_w grid y=16).
//  * gemm_split round-8 body FROZEN (r9/r10/r11 all regressed).
// Stage cfg (T,I,O,C,Gs): s4(256,16,20,0,16) s3(64,144,20,80,64)
//  s2(16,336,77,80,256) s1(4,1332,308,308,1024) s0(1,5328,1229,1232,4096)

#define BDIM 2048
#define OUTW 341

typedef __attribute__((ext_vector_type(8))) short short8;
typedef __attribute__((ext_vector_type(4))) float float4v;

static __device__ __forceinline__ unsigned short f2bf(float f) {
    union { float f; unsigned u; } c{f};
    unsigned r = c.u + 0x7FFF + ((c.u >> 16) & 1);  // RNE
    return (unsigned short)(r >> 16);
}
static __device__ __forceinline__ float bf2f(unsigned short s) {
    union { unsigned u; float f; } c{(unsigned)s << 16};
    return c.f;
}

static __device__ __forceinline__ float fast_tanh(float x) {
    float ax = __builtin_fabsf(x);
    float e  = __builtin_amdgcn_exp2f(ax * 2.8853900817779268f);  // e^{2|x|}
    float r  = 1.f - 2.f * __builtin_amdgcn_rcpf(e + 1.f);
    return __builtin_copysignf(r, x);
}

// scale/shift from accumulated (sum, sumsq): identical expression everywhere.
static __device__ __forceinline__ void bn_ss(float sm, float sq, float g, float bb,
                                             float& scale, float& shift) {
    float mu = sm * (1.f / BDIM);
    float var = sq * (1.f / BDIM) - mu * mu;  // biased, matches jnp.var
    scale = rsqrtf(var + 1e-5f) * g;
    shift = bb - mu * scale;
}

// async global->LDS, 16B/lane: wave-uniform base + lane*16.
static __device__ __forceinline__ void stage16(const void* g, void* ldsBase, int lane) {
#if __has_builtin(__builtin_amdgcn_global_load_lds)
    __builtin_amdgcn_global_load_lds(
        (const __attribute__((address_space(1))) unsigned int*)(uintptr_t)g,
        (__attribute__((address_space(3))) unsigned int*)(unsigned int)(uintptr_t)ldsBase,
        16, 0, 0);
#else
    *(uint4*)((char*)ldsBase + lane * 16) = *(const uint4*)g;
#endif
}

// ---- W[t][I][O] fp32 -> WbT[t][Npad][Kpad] bf16 core ----
static __device__ __forceinline__ void cvt_w_body(const float* Wt, unsigned short* dst,
                                                  int I, int O, int Npad, int Kpad,
                                                  int i0, int o0, int tid) {
    __shared__ unsigned short tile[32][33];
    const int c = tid & 31, r0 = tid >> 5;
    #pragma unroll
    for (int rr = 0; rr < 4; rr++) {
        int i = i0 + r0 + rr * 8, o = o0 + c;
        float v = (i < I && o < O) ? Wt[(size_t)i * O + o] : 0.f;
        tile[r0 + rr * 8][c] = f2bf(v);
    }
    __syncthreads();
    #pragma unroll
    for (int rr = 0; rr < 4; rr++) {
        int o = o0 + r0 + rr * 8, k = i0 + c;
        if (o < Npad) dst[(size_t)o * Kpad + k] = tile[c][r0 + rr * 8];
    }
}

// ---- fused: x pack + W4..W1 cvt + W0 rows [512,1280) cvt + acc zeroing ----
#define PACK_BLOCKS ((BDIM * 512 + BDIM * 24 + 255) / 256)   // 4288
#define CVT_BLOCKS  2896
#define W0P1_BLOCKS (168 * 24)                                // rows 512..1279
__global__ __launch_bounds__(256) void pack_cvt(const float* __restrict__ x,
                                                unsigned short* __restrict__ ain0,
                                                unsigned short* __restrict__ ain1,
                                                const float* __restrict__ W4,
                                                const float* __restrict__ W3,
                                                const float* __restrict__ W2,
                                                const float* __restrict__ W1,
                                                const float* __restrict__ W0,
                                                unsigned short* __restrict__ wbt,
                                                float* __restrict__ acc) {
    int bid = blockIdx.x;
    if (bid < 20) {   // zero the 20,186-float stat accumulators (81KB region)
        int idx = bid * 1024 + threadIdx.x * 4;
        *(float4*)(acc + idx) = make_float4(0.f, 0.f, 0.f, 0.f);
    }
    if (bid < PACK_BLOCKS) {
        const int MAIN = BDIM * 512;          // 8-float units
        int i = bid * 256 + threadIdx.x;
        if (i < MAIN) {
            int b = i >> 9, j = i & 511;
            const float* xp = x + (size_t)b * 4096 + j * 8;
            float4 lo = *(const float4*)xp, hi = *(const float4*)(xp + 4);
            union { unsigned short u[8]; uint4 v4; uint2 v2[2]; } t;
            t.u[0] = f2bf(lo.x); t.u[1] = f2bf(lo.y); t.u[2] = f2bf(lo.z); t.u[3] = f2bf(lo.w);
            t.u[4] = f2bf(hi.x); t.u[5] = f2bf(hi.y); t.u[6] = f2bf(hi.z); t.u[7] = f2bf(hi.w);
            *(uint4*)(ain0 + (size_t)b * 5376 + 1232 + j * 8) = t.v4;       // 16B aligned
            int gi = j * 8, tt = gi >> 10, u = gi & 1023;
            unsigned short* d1 = ain1 + (size_t)b * 5376 + tt * 1344 + 308 + u;  // 8B aligned
            *(uint2*)d1 = t.v2[0];
            *(uint2*)(d1 + 4) = t.v2[1];
            return;
        }
        int zi = i - MAIN;                    // zero pads, uint2 (4-short) units
        const int ZU = BDIM * 12;             // per-buffer zero units
        if (zi < ZU) {                        // ain0: cols [5328,5376)
            int b = zi / 12, u = zi % 12;
            *(uint2*)(ain0 + (size_t)b * 5376 + 5328 + u * 4) = make_uint2(0u, 0u);
        } else if (zi < 2 * ZU) {             // ain1: cols [t*1344+1332, +1344)
            zi -= ZU;
            int b = zi / 12, u = zi % 12, tt = u / 3, k = u % 3;
            *(uint2*)(ain1 + (size_t)b * 5376 + tt * 1344 + 1332 + k * 4) = make_uint2(0u, 0u);
        }
        return;
    }
    bid -= PACK_BLOCKS;
    if (bid >= CVT_BLOCKS) {                  // W0 part1: rows o>=512 (dst free at t=0)
        bid -= CVT_BLOCKS;
        int bx = bid % 168, by = 16 + bid / 168;
        cvt_w_body(W0, wbt, 5328, 1229, 1280, 5376, bx * 32, by * 32, threadIdx.x);
        return;
    }
    const float* W; unsigned short* dst;
    int I, O, Npad, Kpad, gx, gy, local;
    if (bid < 256)       { W = W4; dst = wbt;           I = 16;   O = 20;  Npad = 20;  Kpad = 32;   gx = 1;  gy = 1;  local = bid; }
    else if (bid < 640)  { W = W3; dst = wbt + 163840;  I = 144;  O = 20;  Npad = 20;  Kpad = 192;  gx = 6;  gy = 1;  local = bid - 256; }
    else if (bid < 1216) { W = W2; dst = wbt + 409600;  I = 336;  O = 77;  Npad = 77;  Kpad = 384;  gx = 12; gy = 3;  local = bid - 640; }
    else                 { W = W1; dst = wbt + 882688;  I = 1332; O = 308; Npad = 320; Kpad = 1344; gx = 42; gy = 10; local = bid - 1216; }
    int per = gx * gy;
    int t = local / per, rem = local % per;
    int by = rem / gx, bx = rem % gx;
    cvt_w_body(W + (size_t)t * I * O, dst + (size_t)t * Npad * Kpad,
               I, O, Npad, Kpad, bx * 32, by * 32, threadIdx.x);
}

__global__ __launch_bounds__(256) void cvt_w(const float* __restrict__ W,
                                             unsigned short* __restrict__ WbT,
                                             int I, int O, int Npad, int Kpad) {
    cvt_w_body(W + (size_t)blockIdx.z * I * O, WbT + (size_t)blockIdx.z * Npad * Kpad,
               I, O, Npad, Kpad, blockIdx.x * 32, blockIdx.y * 32, threadIdx.x);
}

// ---- s4 stats pass: MFMA h in-register; atomicAdd column (sum,sumsq) -> acc4.
__global__ __launch_bounds__(256) void s4_stats(
    const unsigned short* __restrict__ xg,   // genes, row stride 5376
    const unsigned short* __restrict__ wbt4, // [256][20][32] bf16
    const float* __restrict__ b4,            // flat [5120]
    float* __restrict__ acc4)                // [2][5120] atomic accumulators
{
    const int cg = blockIdx.x & 31;
    const int rc = blockIdx.x >> 5;
    const int t0 = cg * 8, b0 = rc * 64;
    const int tid = threadIdx.x;
    const int lane = tid & 63, w = tid >> 6;
    const int l15 = lane & 15, quad = lane >> 4;

    __shared__ __align__(16) unsigned short xs[64][168];

    #pragma unroll
    for (int j = 0; j < 4; j++) {
        int i = tid + j * 256;
        int r = i >> 4, gg = i & 15;
        *(uint4*)&xs[r][gg * 8] =
            *(const uint4*)(xg + (size_t)(b0 + r) * 5376 + t0 * 16 + gg * 8);
    }
    if (tid < 128) {
        int r = tid >> 1, gg = 16 + (tid & 1);
        *(uint4*)&xs[r][gg * 8] = make_uint4(0u, 0u, 0u, 0u);
    }
    __syncthreads();

    float4v acc[2][4][2];
    #pragma unroll
    for (int a = 0; a < 2; a++)
        #pragma unroll
        for (int b = 0; b < 4; b++)
            #pragma unroll
            for (int c = 0; c < 2; c++)
                acc[a][b][c] = (float4v){0.f, 0.f, 0.f, 0.f};

    #pragma unroll
    for (int ti = 0; ti < 2; ti++) {
        const int lt = w * 2 + ti;
        const int t = t0 + lt;
        short8 bf[2];
        #pragma unroll
        for (int nf = 0; nf < 2; nf++)
            bf[nf] = *(const short8*)(wbt4 + ((size_t)t * 20 + nf * 16 + l15) * 32 + quad * 8);
        #pragma unroll
        for (int mf = 0; mf < 4; mf++) {
            short8 a = *(const short8*)&xs[mf * 16 + l15][lt * 16 + quad * 8];
            #pragma unroll
            for (int nf = 0; nf < 2; nf++)
                acc[ti][mf][nf] = __builtin_amdgcn_mfma_f32_16x16x32_bf16(a, bf[nf], acc[ti][mf][nf], 0, 0, 0);
        }
    }

    #pragma unroll
    for (int ti = 0; ti < 2; ti++) {
        const int lt = w * 2 + ti;
        #pragma unroll
        for (int nf = 0; nf < 2; nf++) {
            const int o = nf * 16 + l15;
            const int col = (t0 + lt) * 20 + o;
            const bool valid = (o < 20);
            const float bias = valid ? b4[col] : 0.f;
            float s = 0.f, s2 = 0.f;
            #pragma unroll
            for (int mf = 0; mf < 4; mf++)
                #pragma unroll
                for (int r = 0; r < 4; r++) {
                    float v = acc[ti][mf][nf][r] + bias;
                    s += v; s2 += v * v;
                }
            s  += __shfl_xor(s, 16, 64);  s  += __shfl_xor(s, 32, 64);
            s2 += __shfl_xor(s2, 16, 64); s2 += __shfl_xor(s2, 32, 64);
            if (quad == 0 && valid) {
                atomicAdd(acc4 + col, s);
                atomicAdd(acc4 + 5120 + col, s2);
            }
        }
    }
}

// ---- s4+s3 fused: recompute s4 h -> BN(from acc4)+tanh -> act in LDS -> s4
// head -> s3 MFMA -> h3 + atomic col stats -> acc3.
__global__ __launch_bounds__(256) void s4s3_fused(
    const unsigned short* __restrict__ xg,   // genes, row stride 5376
    const unsigned short* __restrict__ wbt4, // [256][20][32]
    const unsigned short* __restrict__ wbt3, // [64][20][192]
    const float* __restrict__ b4,            // [5120]
    const float* __restrict__ acc4,          // [2][5120] final sums
    const float* __restrict__ g4,
    const float* __restrict__ bb4,
    const float* __restrict__ hw4,           // [5120]
    const float* __restrict__ hb4,           // [256]
    const float* __restrict__ b3,            // [1280]
    unsigned short* __restrict__ h3,         // [2048][1280]
    float* __restrict__ acc3,                // [2][1280] atomic accumulators
    float* __restrict__ out)
{
    const int cg = blockIdx.x & 31;
    const int rc = blockIdx.x >> 5;
    const int t0 = cg * 8, b0 = rc * 64;
    const int tid = threadIdx.x;
    const int lane = tid & 63, w = tid >> 6;
    const int l15 = lane & 15, quad = lane >> 4;

    __shared__ __align__(16) unsigned short gs[64][152];
    __shared__ __align__(16) unsigned short as_[64][168];

    #pragma unroll
    for (int j = 0; j < 4; j++) {
        int i = tid + j * 256;
        int r = i >> 4, gg = i & 15;
        *(uint4*)&gs[r][gg * 8] =
            *(const uint4*)(xg + (size_t)(b0 + r) * 5376 + t0 * 16 + gg * 8);
    }
    if (tid < 128) {
        int r = tid >> 1, gg = 16 + (tid & 1);
        *(uint4*)&gs[r][gg * 8] = make_uint4(0u, 0u, 0u, 0u);
    }
    __syncthreads();

    // ---- phase 1: s4 MFMA (identical order to s4_stats)
    float4v acc[2][4][2];
    #pragma unroll
    for (int a = 0; a < 2; a++)
        #pragma unroll
        for (int b = 0; b < 4; b++)
            #pragma unroll
            for (int c = 0; c < 2; c++)
                acc[a][b][c] = (float4v){0.f, 0.f, 0.f, 0.f};

    #pragma unroll
    for (int ti = 0; ti < 2; ti++) {
        const int lt = w * 2 + ti;
        const int t = t0 + lt;
        short8 bf[2];
        #pragma unroll
        for (int nf = 0; nf < 2; nf++)
            bf[nf] = *(const short8*)(wbt4 + ((size_t)t * 20 + nf * 16 + l15) * 32 + quad * 8);
        #pragma unroll
        for (int mf = 0; mf < 4; mf++) {
            short8 a = *(const short8*)&gs[mf * 16 + l15][lt * 16 + quad * 8];
            #pragma unroll
            for (int nf = 0; nf < 2; nf++)
                acc[ti][mf][nf] = __builtin_amdgcn_mfma_f32_16x16x32_bf16(a, bf[nf], acc[ti][mf][nf], 0, 0, 0);
        }
    }

    // ---- phase 2: BN(from acc4)+tanh -> act into as_ + s4 head -> out
    #pragma unroll
    for (int ti = 0; ti < 2; ti++) {
        const int lt = w * 2 + ti;
        const int t4 = t0 + lt;
        float hp[4][4];
        #pragma unroll
        for (int mf = 0; mf < 4; mf++)
            #pragma unroll
            for (int r = 0; r < 4; r++) hp[mf][r] = 0.f;
        #pragma unroll
        for (int nf = 0; nf < 2; nf++) {
            const int o = nf * 16 + l15;
            const int col = t4 * 20 + o;
            const bool valid = (o < 20);
            float scale = 0.f, shp = 0.f, hwv = 0.f;
            if (valid) {
                float sc, sh;
                bn_ss(acc4[col], acc4[5120 + col], g4[col], bb4[col], sc, sh);
                scale = sc;
                shp = b4[col] * sc + sh;
                hwv = hw4[col];
            }
            #pragma unroll
            for (int mf = 0; mf < 4; mf++)
                #pragma unroll
                for (int r = 0; r < 4; r++) {
                    float av = fast_tanh(acc[ti][mf][nf][r] * scale + shp);
                    if (valid)
                        as_[mf * 16 + quad * 4 + r][lt * 20 + o] = f2bf(av);
                    hp[mf][r] += av * hwv;
                }
        }
        const float hbv = hb4[t4];
        #pragma unroll
        for (int mf = 0; mf < 4; mf++)
            #pragma unroll
            for (int r = 0; r < 4; r++) {
                float v = hp[mf][r];
                v += __shfl_xor(v, 1, 64); v += __shfl_xor(v, 2, 64);
                v += __shfl_xor(v, 4, 64); v += __shfl_xor(v, 8, 64);
                if (l15 == 0)
                    out[(size_t)(b0 + mf * 16 + quad * 4 + r) * OUTW + t4] = v + hbv;
            }
    }
    __syncthreads();   // as_ fully written before s3 reads

    // ---- phase 3: s3 MFMA
    const int t3l = w & 1, mh = w >> 1;
    const int t3 = cg * 2 + t3l;
    float4v acc3r[2][2];
    #pragma unroll
    for (int a = 0; a < 2; a++)
        #pragma unroll
        for (int b = 0; b < 2; b++)
            acc3r[a][b] = (float4v){0.f, 0.f, 0.f, 0.f};

    #pragma unroll
    for (int ks = 0; ks < 5; ks++) {
        const int k = ks * 32 + quad * 8;
        short8 bf[2];
        #pragma unroll
        for (int nf = 0; nf < 2; nf++)
            bf[nf] = *(const short8*)(wbt3 + ((size_t)t3 * 20 + nf * 16 + l15) * 192 + ks * 32 + quad * 8);
        #pragma unroll
        for (int mf2 = 0; mf2 < 2; mf2++) {
            const int row = (mh * 2 + mf2) * 16 + l15;
            const unsigned short* ap = (k < 80) ? &as_[row][t3l * 80 + k]
                                                : &gs[row][t3l * 64 + (k - 80)];
            short8 a = *(const short8*)ap;
            #pragma unroll
            for (int nf = 0; nf < 2; nf++)
                acc3r[mf2][nf] = __builtin_amdgcn_mfma_f32_16x16x32_bf16(a, bf[nf], acc3r[mf2][nf], 0, 0, 0);
        }
    }

    // ---- phase 4: h3 + atomic column stats -> acc3
    float ss_[2], ss2_[2];
    #pragma unroll
    for (int nf = 0; nf < 2; nf++) { ss_[nf] = 0.f; ss2_[nf] = 0.f; }
    #pragma unroll
    for (int mf2 = 0; mf2 < 2; mf2++)
        #pragma unroll
        for (int nf = 0; nf < 2; nf++) {
            const int o = nf * 16 + l15;
            const int col = t3 * 20 + o;
            const bool valid = (o < 20);
            const float bias = valid ? b3[col] : 0.f;
            #pragma unroll
            for (int r = 0; r < 4; r++) {
                const int m = (mh * 2 + mf2) * 16 + quad * 4 + r;
                float v = acc3r[mf2][nf][r] + bias;
                if (valid)
                    h3[(size_t)(b0 + m) * 1280 + col] = f2bf(v);
                ss_[nf] += v; ss2_[nf] += v * v;
            }
        }
    #pragma unroll
    for (int nf = 0; nf < 2; nf++) {
        ss_[nf]  += __shfl_xor(ss_[nf], 16, 64);  ss_[nf]  += __shfl_xor(ss_[nf], 32, 64);
        ss2_[nf] += __shfl_xor(ss2_[nf], 16, 64); ss2_[nf] += __shfl_xor(ss2_[nf], 32, 64);
        const int o = nf * 16 + l15;
        if (quad == 0 && o < 20) {
            const int col = t3 * 20 + o;
            atomicAdd(acc3 + col, ss_[nf]);
            atomicAdd(acc3 + 1280 + col, ss2_[nf]);
        }
    }
}

// ---- small-stage GEMM + atomic column stats ----
template <int BN, int BK>
__global__ __launch_bounds__(256) void gemm_small(
    const unsigned short* __restrict__ actb,  // [B][T*C] bf16 (null if C==0)
    const unsigned short* __restrict__ xg,    // bf16 x copy, row stride 5376
    const unsigned short* __restrict__ WbT,   // [T][O][Kpad] bf16
    const float* __restrict__ bias,
    unsigned short* __restrict__ h,           // [B][hstride]
    float* __restrict__ acc,                  // [2][TO] atomic accumulators
    int T, int I, int O, int C, int Gs, int Kpad, int hstride, int TO)
{
    const int t  = blockIdx.z;
    const int b0 = blockIdx.y * 64;
    const int o0 = blockIdx.x * BN;
    const int tid = threadIdx.x;
    const int lane = tid & 63;
    const int w = tid >> 6;
    const int l15 = lane & 15;
    const int quad = lane >> 4;

    constexpr int NF = BN / 32;
    const int wm = (w & 1) * 32;
    const int wn = (w >> 1) * (BN / 2);

    __shared__ __align__(16) unsigned short As[64][BK + 8];
    __shared__ __align__(16) unsigned short Bs[BN][BK + 8];
    __shared__ float ldsS[2][BN], ldsS2[2][BN];

    float4v accr[2][NF];
    #pragma unroll
    for (int a = 0; a < 2; a++)
        #pragma unroll
        for (int b = 0; b < NF; b++)
            accr[a][b] = (float4v){0.f, 0.f, 0.f, 0.f};

    constexpr int GR = BK / 8;
    constexpr int AG = 64 * GR;
    constexpr int BG = BN * GR;
    const size_t actRow = (size_t)T * C;

    for (int k0 = 0; k0 < Kpad; k0 += BK) {
        #pragma unroll
        for (int g = tid; g < AG; g += 256) {
            const int r = g / GR, c8 = g % GR;
            const int k = k0 + c8 * 8;
            const int b = b0 + r;
            uint4 v;
            if (k + 8 <= C) {
                v = *(const uint4*)(actb + (size_t)b * actRow + (size_t)t * C + k);
            } else if (k >= I) {
                v = make_uint4(0u, 0u, 0u, 0u);
            } else {
                v = *(const uint4*)(xg + (size_t)b * 5376 + (size_t)t * Gs + (k - C));
            }
            *(uint4*)&As[r][c8 * 8] = v;
        }
        #pragma unroll
        for (int g = tid; g < BG; g += 256) {
            const int n = g / GR, c8 = g % GR;
            const int o = o0 + n;
            uint4 v = make_uint4(0u, 0u, 0u, 0u);
            if (o < O)
                v = *(const uint4*)(WbT + ((size_t)t * O + o) * Kpad + k0 + c8 * 8);
            *(uint4*)&Bs[n][c8 * 8] = v;
        }
        __syncthreads();
        #pragma unroll
        for (int ks = 0; ks < BK / 32; ks++) {
            const int koff = ks * 32 + quad * 8;
            short8 a0 = *(const short8*)&As[wm + l15][koff];
            short8 a1 = *(const short8*)&As[wm + 16 + l15][koff];
            #pragma unroll
            for (int fn = 0; fn < NF; fn++) {
                short8 bf = *(const short8*)&Bs[wn + fn * 16 + l15][koff];
                accr[0][fn] = __builtin_amdgcn_mfma_f32_16x16x32_bf16(a0, bf, accr[0][fn], 0, 0, 0);
                accr[1][fn] = __builtin_amdgcn_mfma_f32_16x16x32_bf16(a1, bf, accr[1][fn], 0, 0, 0);
            }
        }
        __syncthreads();
    }

    // epilogue + per-thread column partial sums (fp32, pre-rounding)
    float csum[NF], csum2[NF];
    #pragma unroll
    for (int fn = 0; fn < NF; fn++) { csum[fn] = 0.f; csum2[fn] = 0.f; }
    #pragma unroll
    for (int fm = 0; fm < 2; fm++)
        #pragma unroll
        for (int fn = 0; fn < NF; fn++)
            #pragma unroll
            for (int r = 0; r < 4; r++) {
                int m = wm + fm * 16 + quad * 4 + r;
                int o = o0 + wn + fn * 16 + l15;
                if (o < O) {
                    float v = accr[fm][fn][r] + bias[t * O + o];
                    h[(size_t)(b0 + m) * hstride + (size_t)t * O + o] = f2bf(v);
                    csum[fn] += v; csum2[fn] += v * v;
                }
            }
    #pragma unroll
    for (int fn = 0; fn < NF; fn++) {
        csum[fn]  += __shfl_xor(csum[fn], 16, 64);
        csum[fn]  += __shfl_xor(csum[fn], 32, 64);
        csum2[fn] += __shfl_xor(csum2[fn], 16, 64);
        csum2[fn] += __shfl_xor(csum2[fn], 32, 64);
    }
    if (quad == 0) {
        #pragma unroll
        for (int fn = 0; fn < NF; fn++) {
            ldsS[w & 1][wn + fn * 16 + l15]  = csum[fn];
            ldsS2[w & 1][wn + fn * 16 + l15] = csum2[fn];
        }
    }
    __syncthreads();
    if (tid < BN && o0 + tid < O) {
        int col = t * O + o0 + tid;
        atomicAdd(acc + col,      ldsS[0][tid] + ldsS[1][tid]);
        atomicAdd(acc + TO + col, ldsS2[0][tid] + ldsS2[1][tid]);
    }
}

// ---- big-stage GEMM (s1/s0): 128-row tile, BK=32, dbuf LDS, XCD-swizzled 1D grid
// (round-8 proven body, frozen).
template <int BN>
__global__ __launch_bounds__(256) void gemm_split(
    const unsigned short* __restrict__ A,     // [2048][aStride] bf16 (zero-padded)
    const unsigned short* __restrict__ WbT,   // [T][Npad][Kpad] bf16 (zero-padded)
    float* __restrict__ partial,              // [KS][2048][TNpad]
    int aStride, int tStride, int Kpad, int Npad, int KS, int TNpad,
    int nTiles, int TKS)
{
    const int tid = threadIdx.x;
    const int lane = tid & 63, w = tid >> 6;
    const int l15 = lane & 15, quad = lane >> 4;

    // swizzled decode
    const int id = blockIdx.x;
    const int c = id & 7;
    const int tmp = id >> 3;
    const int n = tmp % nTiles;
    const int q = tmp / nTiles;
    const int group = q * 8 + c;
    const int b0 = (group / TKS) * 128;
    const int rem = group % TKS;
    const int t = rem / KS;
    const int ksIdx = rem - t * KS;
    const int n0 = n * BN;

    __shared__ __align__(16) unsigned short As[2][128 * 32];   // 2 x 8 KB
    __shared__ __align__(16) unsigned short Bs[2][BN * 32];    // 2 x 8/4 KB

    const int S = Kpad >> 5;
    const int qb = S / KS, rb = S % KS;
    const int beg = ksIdx * qb + (ksIdx < rb ? ksIdx : rb);
    const int cnt = qb + (ksIdx < rb ? 1 : 0);

    constexpr int NF = BN / 32;
    const int wm = (w & 1) * 64;
    const int wn = (w >> 1) * (BN / 2);

    float4v acc[4][NF];
    #pragma unroll
    for (int a = 0; a < 4; a++)
        #pragma unroll
        for (int b = 0; b < NF; b++)
            acc[a][b] = (float4v){0.f, 0.f, 0.f, 0.f};

    // A staging: 512 granule-slots, 2 calls/wave
    const unsigned short* aSrc[2];
    int aOff[2];
    #pragma unroll
    for (int j = 0; j < 2; j++) {
        int s = (w * 2 + j) * 64 + lane;
        int r = s >> 2, kg = (s & 3) ^ ((r >> 1) & 3);
        aSrc[j] = A + (size_t)(b0 + r) * aStride + (size_t)t * tStride + kg * 8;
        aOff[j] = (w * 2 + j) * 512;           // shorts
    }
    // B staging
    constexpr int BCALLS = (BN == 128) ? 2 : 1;
    const unsigned short* bSrc[BCALLS];
    int bOff[BCALLS];
    #pragma unroll
    for (int j = 0; j < BCALLS; j++) {
        int s = (w * BCALLS + j) * 64 + lane;
        int r = s >> 2, kg = (s & 3) ^ ((r >> 1) & 3);
        bSrc[j] = WbT + ((size_t)t * Npad + n0 + r) * Kpad + kg * 8;
        bOff[j] = (w * BCALLS + j) * 512;
    }

    // prologue: stage step 0 into buf 0
    {
        const int k0 = beg << 5;
        #pragma unroll
        for (int j = 0; j < 2; j++)      stage16(aSrc[j] + k0, &As[0][aOff[j]], lane);
        #pragma unroll
        for (int j = 0; j < BCALLS; j++) stage16(bSrc[j] + k0, &Bs[0][bOff[j]], lane);
    }

    for (int s = 0; s < cnt; s++) {
        const int cur = s & 1;
        __syncthreads();   // drains cur-buf loads (in flight since prev iter) + prev compute
        if (s + 1 < cnt) {
            const int k1 = (beg + s + 1) << 5;
            #pragma unroll
            for (int j = 0; j < 2; j++)      stage16(aSrc[j] + k1, &As[cur ^ 1][aOff[j]], lane);
            #pragma unroll
            for (int j = 0; j < BCALLS; j++) stage16(bSrc[j] + k1, &Bs[cur ^ 1][bOff[j]], lane);
        }
        short8 af[4];
        #pragma unroll
        for (int fm = 0; fm < 4; fm++) {
            int m = wm + fm * 16 + l15;
            int pos = quad ^ ((m >> 1) & 3);
            af[fm] = *(const short8*)&As[cur][(m * 4 + pos) * 8];
        }
        short8 bfr[NF];
        #pragma unroll
        for (int fn = 0; fn < NF; fn++) {
            int nn = wn + fn * 16 + l15;
            int pos = quad ^ ((nn >> 1) & 3);
            bfr[fn] = *(const short8*)&Bs[cur][(nn * 4 + pos) * 8];
        }
        #pragma unroll
        for (int fm = 0; fm < 4; fm++)
            #pragma unroll
            for (int fn = 0; fn < NF; fn++)
                acc[fm][fn] = __builtin_amdgcn_mfma_f32_16x16x32_bf16(af[fm], bfr[fn], acc[fm][fn], 0, 0, 0);
    }

    const size_t pBase = ((size_t)ksIdx * BDIM + b0) * TNpad + (size_t)t * Npad + n0;
    #pragma unroll
    for (int fm = 0; fm < 4; fm++)
        #pragma unroll
        for (int r = 0; r < 4; r++) {
            const int m = wm + fm * 16 + quad * 4 + r;
            float* prow = partial + pBase + (size_t)m * TNpad + wn;
            #pragma unroll
            for (int fn = 0; fn < NF; fn++)
                prow[fn * 16 + l15] = acc[fm][fn][r];
        }
}

// ---- fused split-K reduce + bias + bf16 h store + atomic column stats ----
__global__ __launch_bounds__(256) void reduce_bias_stats(
    const float* __restrict__ partial, const float* __restrict__ bias,
    unsigned short* __restrict__ h, float* __restrict__ acc,
    int T, int O, int Npad, int KS, int hstride, int TO)
{
    __shared__ float redS[4][64], redS2[4][64];
    const int colL = threadIdx.x & 63;
    const int cr = threadIdx.x >> 6;
    const int col = blockIdx.x * 64 + colL;
    const int chunk = blockIdx.y;
    float s = 0.f, s2 = 0.f;
    if (col < TO) {
        int t = col / O, o = col - t * O;
        const size_t TNpad = (size_t)T * Npad;
        const size_t pcol = (size_t)t * Npad + o;
        const float bv = bias[col];
        const int row0 = chunk * 128 + cr * 32;
        for (int r = 0; r < 32; r++) {
            const int row = row0 + r;
            const float* p = partial + (size_t)row * TNpad + pcol;
            float v = bv;
            for (int ks = 0; ks < KS; ks++) v += p[(size_t)ks * BDIM * TNpad];
            h[(size_t)row * hstride + col] = f2bf(v);
            s += v; s2 += v * v;
        }
    }
    redS[cr][colL] = s; redS2[cr][colL] = s2;
    __syncthreads();
    if (cr == 0 && col < TO) {
        float ts  = redS[0][colL] + redS[1][colL] + redS[2][colL] + redS[3][colL];
        float ts2 = redS2[0][colL] + redS2[1][colL] + redS2[2][colL] + redS2[3][colL];
        atomicAdd(acc + col, ts);
        atomicAdd(acc + TO + col, ts2);
    }
}

// ---- vectorized BN(from acc)+tanh+head for O=20 in-place stage (s3) ----
template <int GPT>
__global__ __launch_bounds__(256) void bn_tanh_head_vec(
    unsigned short* hact, const float* __restrict__ acc,
    const float* __restrict__ g, const float* __restrict__ bb,
    const float* __restrict__ hw, const float* __restrict__ hb,
    float* __restrict__ out,
    int T, int rowGran, int RPB, int hstride, int soff, int head_off)
{
    __shared__ float headAcc[256];
    const int tid = threadIdx.x;
    headAcc[tid] = 0.f;
    __syncthreads();
    const int b0 = blockIdx.x * RPB;

    uint2 hv[GPT];
    #pragma unroll
    for (int j = 0; j < GPT; j++) {
        int G = tid + j * 256;
        int r = G / rowGran, gg = G % rowGran;
        hv[j] = *(const uint2*)(hact + (size_t)(b0 + r) * hstride + gg * 4);
    }
    #pragma unroll
    for (int j = 0; j < GPT; j++) {
        int G = tid + j * 256;
        int r = G / rowGran, gg = G % rowGran;
        int c = gg * 4;
        float4 sm = *(const float4*)(acc + c);
        float4 sq = *(const float4*)(acc + soff + c);
        float4 gv = *(const float4*)(g + c);
        float4 bv = *(const float4*)(bb + c);
        float4 w4 = *(const float4*)(hw + c);
        float sc0, sh0, sc1, sh1, sc2, sh2, sc3, sh3;
        bn_ss(sm.x, sq.x, gv.x, bv.x, sc0, sh0);
        bn_ss(sm.y, sq.y, gv.y, bv.y, sc1, sh1);
        bn_ss(sm.z, sq.z, gv.z, bv.z, sc2, sh2);
        bn_ss(sm.w, sq.w, gv.w, bv.w, sc3, sh3);
        union { unsigned short u[4]; uint2 v; } iv, ov;
        iv.v = hv[j];
        float a0 = fast_tanh(bf2f(iv.u[0]) * sc0 + sh0);
        float a1 = fast_tanh(bf2f(iv.u[1]) * sc1 + sh1);
        float a2 = fast_tanh(bf2f(iv.u[2]) * sc2 + sh2);
        float a3 = fast_tanh(bf2f(iv.u[3]) * sc3 + sh3);
        ov.u[0] = f2bf(a0); ov.u[1] = f2bf(a1); ov.u[2] = f2bf(a2); ov.u[3] = f2bf(a3);
        *(uint2*)(hact + (size_t)(b0 + r) * hstride + c) = ov.v;
        float partial = a0 * w4.x + a1 * w4.y + a2 * w4.z + a3 * w4.w;
        int t = gg / 5;
        atomicAdd(&headAcc[r * T + t], partial);
    }
    __syncthreads();
    if (tid < RPB * T) {
        int r = tid / T, t = tid % T;
        out[(size_t)(b0 + r) * OUTW + head_off + t] = headAcc[tid] + hb[t];
    }
}

// ---- BN(from acc) + tanh + strided act store + head — WAVE variant ----
__global__ __launch_bounds__(256) void bn_tanh_head(
    const unsigned short* __restrict__ h, const float* __restrict__ acc,
    const float* __restrict__ g, const float* __restrict__ bb,
    const float* __restrict__ hw, const float* __restrict__ hb,
    unsigned short* __restrict__ actOut, float* __restrict__ out,
    int T, int O, int hstride, int aRow, int GT, int GS, int head_off, int TO)
{
    int wid  = (blockIdx.x * 256 + threadIdx.x) >> 6;
    int lane = threadIdx.x & 63;
    int b = wid / T;
    int t = wid % T;
    const size_t hbase = (size_t)b * hstride + (size_t)t * O;
    const size_t abase = (size_t)b * aRow + (size_t)(t / GT) * GS + (size_t)(t % GT) * O;
    float hsum = 0.f;
    for (int o = lane; o < O; o += 64) {
        int col = t * O + o;
        float sc, sh;
        bn_ss(acc[col], acc[TO + col], g[col], bb[col], sc, sh);
        float a = fast_tanh(bf2f(h[hbase + o]) * sc + sh);
        if (actOut) actOut[abase + o] = f2bf(a);
        hsum += a * hw[col];
    }
    #pragma unroll
    for (int off = 32; off > 0; off >>= 1) hsum += __shfl_down(hsum, off, 64);
    if (lane == 0) out[(size_t)b * OUTW + head_off + t] = hsum + hb[t];
}

extern "C" void kernel_launch(void* const* d_in, const int* in_sizes, int n_in,
                              void* d_out, int out_size, void* d_ws, size_t ws_size,
                              hipStream_t stream)
{
    const float* x = (const float*)d_in[0];
    float* out = (float*)d_out;
    char* ws = (char*)d_ws;

    // ws layout (bytes)
    unsigned short* wbt  = (unsigned short*)(ws);              // 13,762,560
    unsigned short* ain0 = (unsigned short*)(ws + 13762560);   // 22,020,096 (2048x5376)
    unsigned short* bufB = (unsigned short*)(ws + 56754176);   //  5,242,880
    unsigned short* ain1 = (unsigned short*)(ws + 61997056);   // 22,020,096
    unsigned short* bufC = (unsigned short*)(ws + 84017152);   //  5,046,272
    float*          accB = (float*)(ws + 89063424);            //  81 KB stat accumulators
    // overlays (all verified dead at use time):
    float* partial = (float*)(ws + 35782656);   // s1: 21 MB, s0: 41.9 MB (dead regions)
    unsigned short* xg = ain0 + 1232;           // full bf16 x copy, row stride 5376
    // per-stage atomic stat accumulators (sum[TO] then sumsq[TO]):
    float* acc4 = accB;            // 2x5120
    float* acc3 = accB + 10240;    // 2x1280
    float* acc2 = accB + 12800;    // 2x1232
    float* acc1 = accB + 15264;    // 2x1232
    float* acc0 = accB + 17728;    // 2x1229   (total 20,186 floats; 20,480 zeroed)

    const float* W4 = (const float*)d_in[1];  const float* b4 = (const float*)d_in[2];
    const float* g4 = (const float*)d_in[3];  const float* bb4 = (const float*)d_in[4];
    const float* hw4 = (const float*)d_in[5]; const float* hb4 = (const float*)d_in[6];
    const float* W3 = (const float*)d_in[7];  const float* b3 = (const float*)d_in[8];
    const float* g3 = (const float*)d_in[9];  const float* bb3 = (const float*)d_in[10];
    const float* hw3 = (const float*)d_in[11]; const float* hb3 = (const float*)d_in[12];
    const float* W2 = (const float*)d_in[13]; const float* b2 = (const float*)d_in[14];
    const float* g2 = (const float*)d_in[15]; const float* bb2 = (const float*)d_in[16];
    const float* hw2 = (const float*)d_in[17]; const float* hb2 = (const float*)d_in[18];
    const float* W1 = (const float*)d_in[19]; const float* b1 = (const float*)d_in[20];
    const float* g1 = (const float*)d_in[21]; const float* bb1 = (const float*)d_in[22];
    const float* hw1 = (const float*)d_in[23]; const float* hb1 = (const float*)d_in[24];
    const float* W0 = (const float*)d_in[25]; const float* b0_ = (const float*)d_in[26];
    const float* g0 = (const float*)d_in[27]; const float* bb0 = (const float*)d_in[28];
    const float* hw0 = (const float*)d_in[29]; const float* hb0 = (const float*)d_in[30];

    // 1: fused x pack + W4..W1 cvt + W0 rows>=512 cvt + acc zeroing
    pack_cvt<<<PACK_BLOCKS + CVT_BLOCKS + W0P1_BLOCKS, 256, 0, stream>>>(
        x, ain0, ain1, W4, W3, W2, W1, W0, wbt, accB);

    // s4 stats: in-register MFMA h -> atomic column stats -> acc4
    s4_stats<<<1024, 256, 0, stream>>>(xg, wbt, b4, acc4);
    // s4 act recompute (BN from acc4) + s3 GEMM fused: h3 -> bufB, stats -> acc3
    s4s3_fused<<<1024, 256, 0, stream>>>(xg, wbt, wbt + 163840, b4, acc4, g4, bb4,
                                         hw4, hb4, b3, bufB, acc3, out);

    // s3 BN+tanh+head (act3 in-place in bufB)
    bn_tanh_head_vec<5><<<BDIM / 4, 256, 0, stream>>>(bufB, acc3, g3, bb3, hw3, hb3,
                                                      out, 64, 320, 4, 1280, 1280, 256);

    // s2: T=16 I=336 O=77 Kpad=384, WbT @409600 — BN=96, single o-tile
    gemm_small<96, 64><<<dim3(1, 32, 16), 256, 0, stream>>>(bufB, xg, wbt + 409600, b2, bufC,
                                                            acc2, 16, 336, 77, 80, 256, 384, 1232, 1232);
    bn_tanh_head<<<BDIM * 16 / 4, 256, 0, stream>>>(bufC, acc2, g2, bb2, hw2, hb2,
                                                    ain1, out, 16, 77, 1232, 5376, 4, 1344, 320, 1232);

    // s1: T=4 I=1332 O=308 Kpad=1344 Npad=320 KS=2, WbT @882688
    gemm_split<64><<<640, 256, 0, stream>>>(ain1, wbt + 882688, partial,
                                            5376, 1344, 1344, 320, 2, 1280, 5, 8);
    cvt_w<<<dim3(168, 16, 1), 256, 0, stream>>>(W0, wbt, 5328, 1229, 1280, 5376);  // rows [0,512)
    reduce_bias_stats<<<dim3(20, 16), 256, 0, stream>>>(partial, b1, bufC, acc1,
                                                        4, 308, 320, 2, 1232, 1232);
    bn_tanh_head<<<BDIM * 4 / 4, 256, 0, stream>>>(bufC, acc1, g1, bb1, hw1, hb1,
                                                   ain0, out, 4, 308, 1232, 5376, 4, 0, 336, 1232);

    // s0: T=1 I=5328 O=1229 Kpad=5376 Npad=1280 KS=4
    gemm_split<128><<<640, 256, 0, stream>>>(ain0, wbt, partial,
                                             5376, 0, 5376, 1280, 4, 1280, 10, 4);
    reduce_bias_stats<<<dim3(20, 16), 256, 0, stream>>>(partial, b0_, bufC, acc0,
                                                        1, 1229, 1280, 4, 1232, 1229);
    bn_tanh_head<<<BDIM / 4, 256, 0, stream>>>(bufC, acc0, g0, bb0, hw0, hb0,
                                               nullptr, out, 1, 1229, 1232, 1232, 1, 0, 340, 1229);
}

// Round 7
// 372.666 us; speedup vs baseline: 1.1742x; 1.0582x over previous
//
#include <hip/hip_runtime.h>
#include <hip/hip_bf16.h>

// DCell forward, bf16-MFMA. Round-15:
//  * s2_fused: s3 BN+tanh+head folded INTO the s2 GEMM's A-staging path.
//    act3 never materialized -- read raw h3 bf16, apply per-col scale/shift
//    (precomputed from acc3 into LDS per block), tanh, f2bf (bit-identical
//    MFMA input to the old act3). s3 head: each (b,t3) touched by exactly one
//    block -> LDS headAcc + plain store to out. Kills bn_tanh_head_vec
//    dispatch + act3 write/read (10.5MB).
//  * reduce1_cvtw0: s1 split-K reduce + W0 rows [0,512) cvt in ONE launch
//    (flat grid, uniform per-block branch; both depend only on s1-gemm).
//  * 11 -> 9 dispatches. r14 confirmed ~7us per launch boundary on this
//    harness -- boundaries cost more than ~45MB of HBM traffic each.
//  * Atomic (sum,sumsq) stats scheme kept (r14, proven); acc zeroed in
//    pack_cvt. gemm_split round-8 body FROZEN (r9/r10/r11 all regressed).
// Stage cfg (T,I,O,C,Gs): s4(256,16,20,0,16) s3(64,144,20,80,64)
//  s2(16,336,77,80,256) s1(4,1332,308,308,1024) s0(1,5328,1229,1232,4096)

#define BDIM 2048
#define OUTW 341

typedef __attribute__((ext_vector_type(8))) short short8;
typedef __attribute__((ext_vector_type(4))) float float4v;

static __device__ __forceinline__ unsigned short f2bf(float f) {
    union { float f; unsigned u; } c{f};
    unsigned r = c.u + 0x7FFF + ((c.u >> 16) & 1);  // RNE
    return (unsigned short)(r >> 16);
}
static __device__ __forceinline__ float bf2f(unsigned short s) {
    union { unsigned u; float f; } c{(unsigned)s << 16};
    return c.f;
}

static __device__ __forceinline__ float fast_tanh(float x) {
    float ax = __builtin_fabsf(x);
    float e  = __builtin_amdgcn_exp2f(ax * 2.8853900817779268f);  // e^{2|x|}
    float r  = 1.f - 2.f * __builtin_amdgcn_rcpf(e + 1.f);
    return __builtin_copysignf(r, x);
}

// scale/shift from accumulated (sum, sumsq): identical expression everywhere.
static __device__ __forceinline__ void bn_ss(float sm, float sq, float g, float bb,
                                             float& scale, float& shift) {
    float mu = sm * (1.f / BDIM);
    float var = sq * (1.f / BDIM) - mu * mu;  // biased, matches jnp.var
    scale = rsqrtf(var + 1e-5f) * g;
    shift = bb - mu * scale;
}

// async global->LDS, 16B/lane: wave-uniform base + lane*16.
static __device__ __forceinline__ void stage16(const void* g, void* ldsBase, int lane) {
#if __has_builtin(__builtin_amdgcn_global_load_lds)
    __builtin_amdgcn_global_load_lds(
        (const __attribute__((address_space(1))) unsigned int*)(uintptr_t)g,
        (__attribute__((address_space(3))) unsigned int*)(unsigned int)(uintptr_t)ldsBase,
        16, 0, 0);
#else
    *(uint4*)((char*)ldsBase + lane * 16) = *(const uint4*)g;
#endif
}

// ---- W[t][I][O] fp32 -> WbT[t][Npad][Kpad] bf16 core ----
static __device__ __forceinline__ void cvt_w_body(const float* Wt, unsigned short* dst,
                                                  int I, int O, int Npad, int Kpad,
                                                  int i0, int o0, int tid) {
    __shared__ unsigned short tile[32][33];
    const int c = tid & 31, r0 = tid >> 5;
    #pragma unroll
    for (int rr = 0; rr < 4; rr++) {
        int i = i0 + r0 + rr * 8, o = o0 + c;
        float v = (i < I && o < O) ? Wt[(size_t)i * O + o] : 0.f;
        tile[r0 + rr * 8][c] = f2bf(v);
    }
    __syncthreads();
    #pragma unroll
    for (int rr = 0; rr < 4; rr++) {
        int o = o0 + r0 + rr * 8, k = i0 + c;
        if (o < Npad) dst[(size_t)o * Kpad + k] = tile[c][r0 + rr * 8];
    }
}

// ---- fused: x pack + W4..W1 cvt + W0 rows [512,1280) cvt + acc zeroing ----
#define PACK_BLOCKS ((BDIM * 512 + BDIM * 24 + 255) / 256)   // 4288
#define CVT_BLOCKS  2896
#define W0P1_BLOCKS (168 * 24)                                // rows 512..1279
__global__ __launch_bounds__(256) void pack_cvt(const float* __restrict__ x,
                                                unsigned short* __restrict__ ain0,
                                                unsigned short* __restrict__ ain1,
                                                const float* __restrict__ W4,
                                                const float* __restrict__ W3,
                                                const float* __restrict__ W2,
                                                const float* __restrict__ W1,
                                                const float* __restrict__ W0,
                                                unsigned short* __restrict__ wbt,
                                                float* __restrict__ acc) {
    int bid = blockIdx.x;
    if (bid < 20) {   // zero the 20,186-float stat accumulators
        int idx = bid * 1024 + threadIdx.x * 4;
        *(float4*)(acc + idx) = make_float4(0.f, 0.f, 0.f, 0.f);
    }
    if (bid < PACK_BLOCKS) {
        const int MAIN = BDIM * 512;          // 8-float units
        int i = bid * 256 + threadIdx.x;
        if (i < MAIN) {
            int b = i >> 9, j = i & 511;
            const float* xp = x + (size_t)b * 4096 + j * 8;
            float4 lo = *(const float4*)xp, hi = *(const float4*)(xp + 4);
            union { unsigned short u[8]; uint4 v4; uint2 v2[2]; } t;
            t.u[0] = f2bf(lo.x); t.u[1] = f2bf(lo.y); t.u[2] = f2bf(lo.z); t.u[3] = f2bf(lo.w);
            t.u[4] = f2bf(hi.x); t.u[5] = f2bf(hi.y); t.u[6] = f2bf(hi.z); t.u[7] = f2bf(hi.w);
            *(uint4*)(ain0 + (size_t)b * 5376 + 1232 + j * 8) = t.v4;       // 16B aligned
            int gi = j * 8, tt = gi >> 10, u = gi & 1023;
            unsigned short* d1 = ain1 + (size_t)b * 5376 + tt * 1344 + 308 + u;  // 8B aligned
            *(uint2*)d1 = t.v2[0];
            *(uint2*)(d1 + 4) = t.v2[1];
            return;
        }
        int zi = i - MAIN;                    // zero pads, uint2 (4-short) units
        const int ZU = BDIM * 12;             // per-buffer zero units
        if (zi < ZU) {                        // ain0: cols [5328,5376)
            int b = zi / 12, u = zi % 12;
            *(uint2*)(ain0 + (size_t)b * 5376 + 5328 + u * 4) = make_uint2(0u, 0u);
        } else if (zi < 2 * ZU) {             // ain1: cols [t*1344+1332, +1344)
            zi -= ZU;
            int b = zi / 12, u = zi % 12, tt = u / 3, k = u % 3;
            *(uint2*)(ain1 + (size_t)b * 5376 + tt * 1344 + 1332 + k * 4) = make_uint2(0u, 0u);
        }
        return;
    }
    bid -= PACK_BLOCKS;
    if (bid >= CVT_BLOCKS) {                  // W0 part1: rows o>=512 (dst free at t=0)
        bid -= CVT_BLOCKS;
        int bx = bid % 168, by = 16 + bid / 168;
        cvt_w_body(W0, wbt, 5328, 1229, 1280, 5376, bx * 32, by * 32, threadIdx.x);
        return;
    }
    const float* W; unsigned short* dst;
    int I, O, Npad, Kpad, gx, gy, local;
    if (bid < 256)       { W = W4; dst = wbt;           I = 16;   O = 20;  Npad = 20;  Kpad = 32;   gx = 1;  gy = 1;  local = bid; }
    else if (bid < 640)  { W = W3; dst = wbt + 163840;  I = 144;  O = 20;  Npad = 20;  Kpad = 192;  gx = 6;  gy = 1;  local = bid - 256; }
    else if (bid < 1216) { W = W2; dst = wbt + 409600;  I = 336;  O = 77;  Npad = 77;  Kpad = 384;  gx = 12; gy = 3;  local = bid - 640; }
    else                 { W = W1; dst = wbt + 882688;  I = 1332; O = 308; Npad = 320; Kpad = 1344; gx = 42; gy = 10; local = bid - 1216; }
    int per = gx * gy;
    int t = local / per, rem = local % per;
    int by = rem / gx, bx = rem % gx;
    cvt_w_body(W + (size_t)t * I * O, dst + (size_t)t * Npad * Kpad,
               I, O, Npad, Kpad, bx * 32, by * 32, threadIdx.x);
}

// ---- s4 stats pass: MFMA h in-register; atomicAdd column (sum,sumsq) -> acc4.
__global__ __launch_bounds__(256) void s4_stats(
    const unsigned short* __restrict__ xg,   // genes, row stride 5376
    const unsigned short* __restrict__ wbt4, // [256][20][32] bf16
    const float* __restrict__ b4,            // flat [5120]
    float* __restrict__ acc4)                // [2][5120] atomic accumulators
{
    const int cg = blockIdx.x & 31;
    const int rc = blockIdx.x >> 5;
    const int t0 = cg * 8, b0 = rc * 64;
    const int tid = threadIdx.x;
    const int lane = tid & 63, w = tid >> 6;
    const int l15 = lane & 15, quad = lane >> 4;

    __shared__ __align__(16) unsigned short xs[64][168];

    #pragma unroll
    for (int j = 0; j < 4; j++) {
        int i = tid + j * 256;
        int r = i >> 4, gg = i & 15;
        *(uint4*)&xs[r][gg * 8] =
            *(const uint4*)(xg + (size_t)(b0 + r) * 5376 + t0 * 16 + gg * 8);
    }
    if (tid < 128) {
        int r = tid >> 1, gg = 16 + (tid & 1);
        *(uint4*)&xs[r][gg * 8] = make_uint4(0u, 0u, 0u, 0u);
    }
    __syncthreads();

    float4v acc[2][4][2];
    #pragma unroll
    for (int a = 0; a < 2; a++)
        #pragma unroll
        for (int b = 0; b < 4; b++)
            #pragma unroll
            for (int c = 0; c < 2; c++)
                acc[a][b][c] = (float4v){0.f, 0.f, 0.f, 0.f};

    #pragma unroll
    for (int ti = 0; ti < 2; ti++) {
        const int lt = w * 2 + ti;
        const int t = t0 + lt;
        short8 bf[2];
        #pragma unroll
        for (int nf = 0; nf < 2; nf++)
            bf[nf] = *(const short8*)(wbt4 + ((size_t)t * 20 + nf * 16 + l15) * 32 + quad * 8);
        #pragma unroll
        for (int mf = 0; mf < 4; mf++) {
            short8 a = *(const short8*)&xs[mf * 16 + l15][lt * 16 + quad * 8];
            #pragma unroll
            for (int nf = 0; nf < 2; nf++)
                acc[ti][mf][nf] = __builtin_amdgcn_mfma_f32_16x16x32_bf16(a, bf[nf], acc[ti][mf][nf], 0, 0, 0);
        }
    }

    #pragma unroll
    for (int ti = 0; ti < 2; ti++) {
        const int lt = w * 2 + ti;
        #pragma unroll
        for (int nf = 0; nf < 2; nf++) {
            const int o = nf * 16 + l15;
            const int col = (t0 + lt) * 20 + o;
            const bool valid = (o < 20);
            const float bias = valid ? b4[col] : 0.f;
            float s = 0.f, s2 = 0.f;
            #pragma unroll
            for (int mf = 0; mf < 4; mf++)
                #pragma unroll
                for (int r = 0; r < 4; r++) {
                    float v = acc[ti][mf][nf][r] + bias;
                    s += v; s2 += v * v;
                }
            s  += __shfl_xor(s, 16, 64);  s  += __shfl_xor(s, 32, 64);
            s2 += __shfl_xor(s2, 16, 64); s2 += __shfl_xor(s2, 32, 64);
            if (quad == 0 && valid) {
                atomicAdd(acc4 + col, s);
                atomicAdd(acc4 + 5120 + col, s2);
            }
        }
    }
}

// ---- s4+s3 fused: recompute s4 h -> BN(from acc4)+tanh -> act in LDS -> s4
// head -> s3 MFMA -> h3 + atomic col stats -> acc3.
__global__ __launch_bounds__(256) void s4s3_fused(
    const unsigned short* __restrict__ xg,   // genes, row stride 5376
    const unsigned short* __restrict__ wbt4, // [256][20][32]
    const unsigned short* __restrict__ wbt3, // [64][20][192]
    const float* __restrict__ b4,            // [5120]
    const float* __restrict__ acc4,          // [2][5120] final sums
    const float* __restrict__ g4,
    const float* __restrict__ bb4,
    const float* __restrict__ hw4,           // [5120]
    const float* __restrict__ hb4,           // [256]
    const float* __restrict__ b3,            // [1280]
    unsigned short* __restrict__ h3,         // [2048][1280]
    float* __restrict__ acc3,                // [2][1280] atomic accumulators
    float* __restrict__ out)
{
    const int cg = blockIdx.x & 31;
    const int rc = blockIdx.x >> 5;
    const int t0 = cg * 8, b0 = rc * 64;
    const int tid = threadIdx.x;
    const int lane = tid & 63, w = tid >> 6;
    const int l15 = lane & 15, quad = lane >> 4;

    __shared__ __align__(16) unsigned short gs[64][152];
    __shared__ __align__(16) unsigned short as_[64][168];

    #pragma unroll
    for (int j = 0; j < 4; j++) {
        int i = tid + j * 256;
        int r = i >> 4, gg = i & 15;
        *(uint4*)&gs[r][gg * 8] =
            *(const uint4*)(xg + (size_t)(b0 + r) * 5376 + t0 * 16 + gg * 8);
    }
    if (tid < 128) {
        int r = tid >> 1, gg = 16 + (tid & 1);
        *(uint4*)&gs[r][gg * 8] = make_uint4(0u, 0u, 0u, 0u);
    }
    __syncthreads();

    // ---- phase 1: s4 MFMA (identical order to s4_stats)
    float4v acc[2][4][2];
    #pragma unroll
    for (int a = 0; a < 2; a++)
        #pragma unroll
        for (int b = 0; b < 4; b++)
            #pragma unroll
            for (int c = 0; c < 2; c++)
                acc[a][b][c] = (float4v){0.f, 0.f, 0.f, 0.f};

    #pragma unroll
    for (int ti = 0; ti < 2; ti++) {
        const int lt = w * 2 + ti;
        const int t = t0 + lt;
        short8 bf[2];
        #pragma unroll
        for (int nf = 0; nf < 2; nf++)
            bf[nf] = *(const short8*)(wbt4 + ((size_t)t * 20 + nf * 16 + l15) * 32 + quad * 8);
        #pragma unroll
        for (int mf = 0; mf < 4; mf++) {
            short8 a = *(const short8*)&gs[mf * 16 + l15][lt * 16 + quad * 8];
            #pragma unroll
            for (int nf = 0; nf < 2; nf++)
                acc[ti][mf][nf] = __builtin_amdgcn_mfma_f32_16x16x32_bf16(a, bf[nf], acc[ti][mf][nf], 0, 0, 0);
        }
    }

    // ---- phase 2: BN(from acc4)+tanh -> act into as_ + s4 head -> out
    #pragma unroll
    for (int ti = 0; ti < 2; ti++) {
        const int lt = w * 2 + ti;
        const int t4 = t0 + lt;
        float hp[4][4];
        #pragma unroll
        for (int mf = 0; mf < 4; mf++)
            #pragma unroll
            for (int r = 0; r < 4; r++) hp[mf][r] = 0.f;
        #pragma unroll
        for (int nf = 0; nf < 2; nf++) {
            const int o = nf * 16 + l15;
            const int col = t4 * 20 + o;
            const bool valid = (o < 20);
            float scale = 0.f, shp = 0.f, hwv = 0.f;
            if (valid) {
                float sc, sh;
                bn_ss(acc4[col], acc4[5120 + col], g4[col], bb4[col], sc, sh);
                scale = sc;
                shp = b4[col] * sc + sh;
                hwv = hw4[col];
            }
            #pragma unroll
            for (int mf = 0; mf < 4; mf++)
                #pragma unroll
                for (int r = 0; r < 4; r++) {
                    float av = fast_tanh(acc[ti][mf][nf][r] * scale + shp);
                    if (valid)
                        as_[mf * 16 + quad * 4 + r][lt * 20 + o] = f2bf(av);
                    hp[mf][r] += av * hwv;
                }
        }
        const float hbv = hb4[t4];
        #pragma unroll
        for (int mf = 0; mf < 4; mf++)
            #pragma unroll
            for (int r = 0; r < 4; r++) {
                float v = hp[mf][r];
                v += __shfl_xor(v, 1, 64); v += __shfl_xor(v, 2, 64);
                v += __shfl_xor(v, 4, 64); v += __shfl_xor(v, 8, 64);
                if (l15 == 0)
                    out[(size_t)(b0 + mf * 16 + quad * 4 + r) * OUTW + t4] = v + hbv;
            }
    }
    __syncthreads();   // as_ fully written before s3 reads

    // ---- phase 3: s3 MFMA
    const int t3l = w & 1, mh = w >> 1;
    const int t3 = cg * 2 + t3l;
    float4v acc3r[2][2];
    #pragma unroll
    for (int a = 0; a < 2; a++)
        #pragma unroll
        for (int b = 0; b < 2; b++)
            acc3r[a][b] = (float4v){0.f, 0.f, 0.f, 0.f};

    #pragma unroll
    for (int ks = 0; ks < 5; ks++) {
        const int k = ks * 32 + quad * 8;
        short8 bf[2];
        #pragma unroll
        for (int nf = 0; nf < 2; nf++)
            bf[nf] = *(const short8*)(wbt3 + ((size_t)t3 * 20 + nf * 16 + l15) * 192 + ks * 32 + quad * 8);
        #pragma unroll
        for (int mf2 = 0; mf2 < 2; mf2++) {
            const int row = (mh * 2 + mf2) * 16 + l15;
            const unsigned short* ap = (k < 80) ? &as_[row][t3l * 80 + k]
                                                : &gs[row][t3l * 64 + (k - 80)];
            short8 a = *(const short8*)ap;
            #pragma unroll
            for (int nf = 0; nf < 2; nf++)
                acc3r[mf2][nf] = __builtin_amdgcn_mfma_f32_16x16x32_bf16(a, bf[nf], acc3r[mf2][nf], 0, 0, 0);
        }
    }

    // ---- phase 4: h3 + atomic column stats -> acc3
    float ss_[2], ss2_[2];
    #pragma unroll
    for (int nf = 0; nf < 2; nf++) { ss_[nf] = 0.f; ss2_[nf] = 0.f; }
    #pragma unroll
    for (int mf2 = 0; mf2 < 2; mf2++)
        #pragma unroll
        for (int nf = 0; nf < 2; nf++) {
            const int o = nf * 16 + l15;
            const int col = t3 * 20 + o;
            const bool valid = (o < 20);
            const float bias = valid ? b3[col] : 0.f;
            #pragma unroll
            for (int r = 0; r < 4; r++) {
                const int m = (mh * 2 + mf2) * 16 + quad * 4 + r;
                float v = acc3r[mf2][nf][r] + bias;
                if (valid)
                    h3[(size_t)(b0 + m) * 1280 + col] = f2bf(v);
                ss_[nf] += v; ss2_[nf] += v * v;
            }
        }
    #pragma unroll
    for (int nf = 0; nf < 2; nf++) {
        ss_[nf]  += __shfl_xor(ss_[nf], 16, 64);  ss_[nf]  += __shfl_xor(ss_[nf], 32, 64);
        ss2_[nf] += __shfl_xor(ss2_[nf], 16, 64); ss2_[nf] += __shfl_xor(ss2_[nf], 32, 64);
        const int o = nf * 16 + l15;
        if (quad == 0 && o < 20) {
            const int col = t3 * 20 + o;
            atomicAdd(acc3 + col, ss_[nf]);
            atomicAdd(acc3 + 1280 + col, ss2_[nf]);
        }
    }
}

// ---- s2 GEMM + on-the-fly act3 (BN+tanh from acc3) + s3 head + s2 stats ----
// Replaces bn_tanh_head_vec(s3) + gemm_small(s2). act3 never materialized.
// grid dim3(1,32,16): y = 64-row chunk, z = t2. BN=96 single o-tile, BK=64.
// Each (b,t3) head is owned by exactly one block -> plain store, no atomics.
__global__ __launch_bounds__(256) void s2_fused(
    const unsigned short* __restrict__ h3,    // [2048][1280] bf16 (raw pre-BN)
    const unsigned short* __restrict__ xg,    // bf16 x copy, row stride 5376
    const unsigned short* __restrict__ WbT,   // s2 region: [16][77][384]
    const float* __restrict__ acc3,           // [2][1280] s3 stats (complete)
    const float* __restrict__ g3, const float* __restrict__ bb3,
    const float* __restrict__ hw3, const float* __restrict__ hb3,
    const float* __restrict__ b2,
    unsigned short* __restrict__ h,           // [2048][1232]
    float* __restrict__ acc2,                 // [2][1232] atomic accumulators
    float* __restrict__ out)
{
    constexpr int BN = 96, BK = 64;
    constexpr int I = 336, O = 77, C = 80, Gs = 256, Kpad = 384;
    constexpr int hstride = 1232, TO = 1232;
    const int t  = blockIdx.z;
    const int b0 = blockIdx.y * 64;
    const int tid = threadIdx.x;
    const int lane = tid & 63;
    const int w = tid >> 6;
    const int l15 = lane & 15;
    const int quad = lane >> 4;

    constexpr int NF = BN / 32;               // 3
    const int wm = (w & 1) * 32;
    const int wn = (w >> 1) * (BN / 2);       // 0 / 48

    __shared__ __align__(16) unsigned short As[64][BK + 8];
    __shared__ __align__(16) unsigned short Bs[BN][BK + 8];
    __shared__ float ldsS[2][BN], ldsS2[2][BN];
    __shared__ float scL[80], shL[80], hwL[80];
    __shared__ float headAcc[64][4];

    if (tid < 80) {
        int col = t * 80 + tid;
        float sc, sh;
        bn_ss(acc3[col], acc3[1280 + col], g3[col], bb3[col], sc, sh);
        scL[tid] = sc; shL[tid] = sh; hwL[tid] = hw3[col];
    }
    headAcc[tid >> 2][tid & 3] = 0.f;
    __syncthreads();

    float4v accr[2][NF];
    #pragma unroll
    for (int a = 0; a < 2; a++)
        #pragma unroll
        for (int b = 0; b < NF; b++)
            accr[a][b] = (float4v){0.f, 0.f, 0.f, 0.f};

    constexpr int GR = BK / 8;     // 8
    constexpr int AG = 64 * GR;    // 512
    constexpr int BG = BN * GR;    // 768

    for (int k0 = 0; k0 < Kpad; k0 += BK) {
        #pragma unroll
        for (int g = tid; g < AG; g += 256) {
            const int r = g / GR, c8 = g % GR;
            const int k = k0 + c8 * 8;
            const int b = b0 + r;
            if (k + 8 <= C) {
                // act3 on the fly from raw h3 (bit-identical to old stored act3)
                union { unsigned short u[8]; uint4 v; } hi_, ho;
                hi_.v = *(const uint4*)(h3 + (size_t)b * 1280 + t * 80 + k);
                const int tA = k / 20, tB = (k + 7) / 20;
                float pA = 0.f, pB = 0.f;
                #pragma unroll
                for (int j = 0; j < 8; j++) {
                    const int kk = k + j;
                    float av = fast_tanh(bf2f(hi_.u[j]) * scL[kk] + shL[kk]);
                    ho.u[j] = f2bf(av);
                    float pr = av * hwL[kk];
                    if (kk / 20 == tA) pA += pr; else pB += pr;
                }
                atomicAdd(&headAcc[r][tA], pA);
                if (tB != tA) atomicAdd(&headAcc[r][tB], pB);
                *(uint4*)&As[r][c8 * 8] = ho.v;
            } else if (k >= I) {
                *(uint4*)&As[r][c8 * 8] = make_uint4(0u, 0u, 0u, 0u);
            } else {
                *(uint4*)&As[r][c8 * 8] =
                    *(const uint4*)(xg + (size_t)b * 5376 + t * Gs + (k - C));
            }
        }
        #pragma unroll
        for (int g = tid; g < BG; g += 256) {
            const int n = g / GR, c8 = g % GR;
            uint4 v = make_uint4(0u, 0u, 0u, 0u);
            if (n < O)
                v = *(const uint4*)(WbT + ((size_t)t * O + n) * Kpad + k0 + c8 * 8);
            *(uint4*)&Bs[n][c8 * 8] = v;
        }
        __syncthreads();
        #pragma unroll
        for (int ks = 0; ks < BK / 32; ks++) {
            const int koff = ks * 32 + quad * 8;
            short8 a0 = *(const short8*)&As[wm + l15][koff];
            short8 a1 = *(const short8*)&As[wm + 16 + l15][koff];
            #pragma unroll
            for (int fn = 0; fn < NF; fn++) {
                short8 bf = *(const short8*)&Bs[wn + fn * 16 + l15][koff];
                accr[0][fn] = __builtin_amdgcn_mfma_f32_16x16x32_bf16(a0, bf, accr[0][fn], 0, 0, 0);
                accr[1][fn] = __builtin_amdgcn_mfma_f32_16x16x32_bf16(a1, bf, accr[1][fn], 0, 0, 0);
            }
        }
        __syncthreads();
    }

    // s3 head out: headAcc complete (act granules staged before final sync).
    {
        const int r = tid >> 2, t3l = tid & 3;
        const int t3 = t * 4 + t3l;
        out[(size_t)(b0 + r) * OUTW + 256 + t3] = headAcc[r][t3l] + hb3[t3];
    }

    // epilogue + per-thread column partial sums (fp32, pre-rounding)
    float csum[NF], csum2[NF];
    #pragma unroll
    for (int fn = 0; fn < NF; fn++) { csum[fn] = 0.f; csum2[fn] = 0.f; }
    #pragma unroll
    for (int fm = 0; fm < 2; fm++)
        #pragma unroll
        for (int fn = 0; fn < NF; fn++)
            #pragma unroll
            for (int r = 0; r < 4; r++) {
                int m = wm + fm * 16 + quad * 4 + r;
                int o = wn + fn * 16 + l15;
                if (o < O) {
                    float v = accr[fm][fn][r] + b2[t * O + o];
                    h[(size_t)(b0 + m) * hstride + (size_t)t * O + o] = f2bf(v);
                    csum[fn] += v; csum2[fn] += v * v;
                }
            }
    #pragma unroll
    for (int fn = 0; fn < NF; fn++) {
        csum[fn]  += __shfl_xor(csum[fn], 16, 64);
        csum[fn]  += __shfl_xor(csum[fn], 32, 64);
        csum2[fn] += __shfl_xor(csum2[fn], 16, 64);
        csum2[fn] += __shfl_xor(csum2[fn], 32, 64);
    }
    if (quad == 0) {
        #pragma unroll
        for (int fn = 0; fn < NF; fn++) {
            ldsS[w & 1][wn + fn * 16 + l15]  = csum[fn];
            ldsS2[w & 1][wn + fn * 16 + l15] = csum2[fn];
        }
    }
    __syncthreads();
    if (tid < BN && tid < O) {
        int col = t * O + tid;
        atomicAdd(acc2 + col,      ldsS[0][tid] + ldsS[1][tid]);
        atomicAdd(acc2 + TO + col, ldsS2[0][tid] + ldsS2[1][tid]);
    }
}

// ---- big-stage GEMM (s1/s0): 128-row tile, BK=32, dbuf LDS, XCD-swizzled 1D grid
// (round-8 proven body, frozen).
template <int BN>
__global__ __launch_bounds__(256) void gemm_split(
    const unsigned short* __restrict__ A,     // [2048][aStride] bf16 (zero-padded)
    const unsigned short* __restrict__ WbT,   // [T][Npad][Kpad] bf16 (zero-padded)
    float* __restrict__ partial,              // [KS][2048][TNpad]
    int aStride, int tStride, int Kpad, int Npad, int KS, int TNpad,
    int nTiles, int TKS)
{
    const int tid = threadIdx.x;
    const int lane = tid & 63, w = tid >> 6;
    const int l15 = lane & 15, quad = lane >> 4;

    // swizzled decode
    const int id = blockIdx.x;
    const int c = id & 7;
    const int tmp = id >> 3;
    const int n = tmp % nTiles;
    const int q = tmp / nTiles;
    const int group = q * 8 + c;
    const int b0 = (group / TKS) * 128;
    const int rem = group % TKS;
    const int t = rem / KS;
    const int ksIdx = rem - t * KS;
    const int n0 = n * BN;

    __shared__ __align__(16) unsigned short As[2][128 * 32];   // 2 x 8 KB
    __shared__ __align__(16) unsigned short Bs[2][BN * 32];    // 2 x 8/4 KB

    const int S = Kpad >> 5;
    const int qb = S / KS, rb = S % KS;
    const int beg = ksIdx * qb + (ksIdx < rb ? ksIdx : rb);
    const int cnt = qb + (ksIdx < rb ? 1 : 0);

    constexpr int NF = BN / 32;
    const int wm = (w & 1) * 64;
    const int wn = (w >> 1) * (BN / 2);

    float4v acc[4][NF];
    #pragma unroll
    for (int a = 0; a < 4; a++)
        #pragma unroll
        for (int b = 0; b < NF; b++)
            acc[a][b] = (float4v){0.f, 0.f, 0.f, 0.f};

    // A staging: 512 granule-slots, 2 calls/wave
    const unsigned short* aSrc[2];
    int aOff[2];
    #pragma unroll
    for (int j = 0; j < 2; j++) {
        int s = (w * 2 + j) * 64 + lane;
        int r = s >> 2, kg = (s & 3) ^ ((r >> 1) & 3);
        aSrc[j] = A + (size_t)(b0 + r) * aStride + (size_t)t * tStride + kg * 8;
        aOff[j] = (w * 2 + j) * 512;           // shorts
    }
    // B staging
    constexpr int BCALLS = (BN == 128) ? 2 : 1;
    const unsigned short* bSrc[BCALLS];
    int bOff[BCALLS];
    #pragma unroll
    for (int j = 0; j < BCALLS; j++) {
        int s = (w * BCALLS + j) * 64 + lane;
        int r = s >> 2, kg = (s & 3) ^ ((r >> 1) & 3);
        bSrc[j] = WbT + ((size_t)t * Npad + n0 + r) * Kpad + kg * 8;
        bOff[j] = (w * BCALLS + j) * 512;
    }

    // prologue: stage step 0 into buf 0
    {
        const int k0 = beg << 5;
        #pragma unroll
        for (int j = 0; j < 2; j++)      stage16(aSrc[j] + k0, &As[0][aOff[j]], lane);
        #pragma unroll
        for (int j = 0; j < BCALLS; j++) stage16(bSrc[j] + k0, &Bs[0][bOff[j]], lane);
    }

    for (int s = 0; s < cnt; s++) {
        const int cur = s & 1;
        __syncthreads();   // drains cur-buf loads (in flight since prev iter) + prev compute
        if (s + 1 < cnt) {
            const int k1 = (beg + s + 1) << 5;
            #pragma unroll
            for (int j = 0; j < 2; j++)      stage16(aSrc[j] + k1, &As[cur ^ 1][aOff[j]], lane);
            #pragma unroll
            for (int j = 0; j < BCALLS; j++) stage16(bSrc[j] + k1, &Bs[cur ^ 1][bOff[j]], lane);
        }
        short8 af[4];
        #pragma unroll
        for (int fm = 0; fm < 4; fm++) {
            int m = wm + fm * 16 + l15;
            int pos = quad ^ ((m >> 1) & 3);
            af[fm] = *(const short8*)&As[cur][(m * 4 + pos) * 8];
        }
        short8 bfr[NF];
        #pragma unroll
        for (int fn = 0; fn < NF; fn++) {
            int nn = wn + fn * 16 + l15;
            int pos = quad ^ ((nn >> 1) & 3);
            bfr[fn] = *(const short8*)&Bs[cur][(nn * 4 + pos) * 8];
        }
        #pragma unroll
        for (int fm = 0; fm < 4; fm++)
            #pragma unroll
            for (int fn = 0; fn < NF; fn++)
                acc[fm][fn] = __builtin_amdgcn_mfma_f32_16x16x32_bf16(af[fm], bfr[fn], acc[fm][fn], 0, 0, 0);
    }

    const size_t pBase = ((size_t)ksIdx * BDIM + b0) * TNpad + (size_t)t * Npad + n0;
    #pragma unroll
    for (int fm = 0; fm < 4; fm++)
        #pragma unroll
        for (int r = 0; r < 4; r++) {
            const int m = wm + fm * 16 + quad * 4 + r;
            float* prow = partial + pBase + (size_t)m * TNpad + wn;
            #pragma unroll
            for (int fn = 0; fn < NF; fn++)
                prow[fn * 16 + l15] = acc[fm][fn][r];
        }
}

// ---- s1 split-K reduce + W0 rows [0,512) cvt, one launch (flat grid) ----
// blocks [0,320): reduce (col-group = bid%20, chunk = bid/20);
// blocks [320,3008): cvt_w_body W0 rows by*32, by in [0,16).
__global__ __launch_bounds__(256) void reduce1_cvtw0(
    const float* __restrict__ partial, const float* __restrict__ bias,
    unsigned short* __restrict__ h, float* __restrict__ acc,
    const float* __restrict__ W0, unsigned short* __restrict__ wbt)
{
    const int bid = blockIdx.x;
    if (bid >= 320) {
        int local = bid - 320;
        int bx = local % 168, by = local / 168;
        cvt_w_body(W0, wbt, 5328, 1229, 1280, 5376, bx * 32, by * 32, threadIdx.x);
        return;
    }
    constexpr int T = 4, O = 308, Npad = 320, KS = 2, hstride = 1232, TO = 1232;
    __shared__ float redS[4][64], redS2[4][64];
    const int colL = threadIdx.x & 63;
    const int cr = threadIdx.x >> 6;
    const int col = (bid % 20) * 64 + colL;
    const int chunk = bid / 20;
    float s = 0.f, s2 = 0.f;
    if (col < TO) {
        int t = col / O, o = col - t * O;
        const size_t TNpad = (size_t)T * Npad;
        const size_t pcol = (size_t)t * Npad + o;
        const float bv = bias[col];
        const int row0 = chunk * 128 + cr * 32;
        for (int r = 0; r < 32; r++) {
            const int row = row0 + r;
            const float* p = partial + (size_t)row * TNpad + pcol;
            float v = bv;
            for (int ks = 0; ks < KS; ks++) v += p[(size_t)ks * BDIM * TNpad];
            h[(size_t)row * hstride + col] = f2bf(v);
            s += v; s2 += v * v;
        }
    }
    redS[cr][colL] = s; redS2[cr][colL] = s2;
    __syncthreads();
    if (cr == 0 && col < TO) {
        float ts  = redS[0][colL] + redS[1][colL] + redS[2][colL] + redS[3][colL];
        float ts2 = redS2[0][colL] + redS2[1][colL] + redS2[2][colL] + redS2[3][colL];
        atomicAdd(acc + col, ts);
        atomicAdd(acc + TO + col, ts2);
    }
}

// ---- fused split-K reduce + bias + bf16 h store + atomic column stats (s0) ----
__global__ __launch_bounds__(256) void reduce_bias_stats(
    const float* __restrict__ partial, const float* __restrict__ bias,
    unsigned short* __restrict__ h, float* __restrict__ acc,
    int T, int O, int Npad, int KS, int hstride, int TO)
{
    __shared__ float redS[4][64], redS2[4][64];
    const int colL = threadIdx.x & 63;
    const int cr = threadIdx.x >> 6;
    const int col = blockIdx.x * 64 + colL;
    const int chunk = blockIdx.y;
    float s = 0.f, s2 = 0.f;
    if (col < TO) {
        int t = col / O, o = col - t * O;
        const size_t TNpad = (size_t)T * Npad;
        const size_t pcol = (size_t)t * Npad + o;
        const float bv = bias[col];
        const int row0 = chunk * 128 + cr * 32;
        for (int r = 0; r < 32; r++) {
            const int row = row0 + r;
            const float* p = partial + (size_t)row * TNpad + pcol;
            float v = bv;
            for (int ks = 0; ks < KS; ks++) v += p[(size_t)ks * BDIM * TNpad];
            h[(size_t)row * hstride + col] = f2bf(v);
            s += v; s2 += v * v;
        }
    }
    redS[cr][colL] = s; redS2[cr][colL] = s2;
    __syncthreads();
    if (cr == 0 && col < TO) {
        float ts  = redS[0][colL] + redS[1][colL] + redS[2][colL] + redS[3][colL];
        float ts2 = redS2[0][colL] + redS2[1][colL] + redS2[2][colL] + redS2[3][colL];
        atomicAdd(acc + col, ts);
        atomicAdd(acc + TO + col, ts2);
    }
}

// ---- BN(from acc) + tanh + strided act store + head — WAVE variant ----
__global__ __launch_bounds__(256) void bn_tanh_head(
    const unsigned short* __restrict__ h, const float* __restrict__ acc,
    const float* __restrict__ g, const float* __restrict__ bb,
    const float* __restrict__ hw, const float* __restrict__ hb,
    unsigned short* __restrict__ actOut, float* __restrict__ out,
    int T, int O, int hstride, int aRow, int GT, int GS, int head_off, int TO)
{
    int wid  = (blockIdx.x * 256 + threadIdx.x) >> 6;
    int lane = threadIdx.x & 63;
    int b = wid / T;
    int t = wid % T;
    const size_t hbase = (size_t)b * hstride + (size_t)t * O;
    const size_t abase = (size_t)b * aRow + (size_t)(t / GT) * GS + (size_t)(t % GT) * O;
    float hsum = 0.f;
    for (int o = lane; o < O; o += 64) {
        int col = t * O + o;
        float sc, sh;
        bn_ss(acc[col], acc[TO + col], g[col], bb[col], sc, sh);
        float a = fast_tanh(bf2f(h[hbase + o]) * sc + sh);
        if (actOut) actOut[abase + o] = f2bf(a);
        hsum += a * hw[col];
    }
    #pragma unroll
    for (int off = 32; off > 0; off >>= 1) hsum += __shfl_down(hsum, off, 64);
    if (lane == 0) out[(size_t)b * OUTW + head_off + t] = hsum + hb[t];
}

extern "C" void kernel_launch(void* const* d_in, const int* in_sizes, int n_in,
                              void* d_out, int out_size, void* d_ws, size_t ws_size,
                              hipStream_t stream)
{
    const float* x = (const float*)d_in[0];
    float* out = (float*)d_out;
    char* ws = (char*)d_ws;

    // ws layout (bytes)
    unsigned short* wbt  = (unsigned short*)(ws);              // 13,762,560
    unsigned short* ain0 = (unsigned short*)(ws + 13762560);   // 22,020,096 (2048x5376)
    unsigned short* bufB = (unsigned short*)(ws + 56754176);   //  5,242,880
    unsigned short* ain1 = (unsigned short*)(ws + 61997056);   // 22,020,096
    unsigned short* bufC = (unsigned short*)(ws + 84017152);   //  5,046,272
    float*          accB = (float*)(ws + 89063424);            //  81 KB stat accumulators
    // overlays (all verified dead at use time):
    float* partial = (float*)(ws + 35782656);   // s1: 21 MB, s0: 41.9 MB (dead regions)
    unsigned short* xg = ain0 + 1232;           // full bf16 x copy, row stride 5376
    // per-stage atomic stat accumulators (sum[TO] then sumsq[TO]):
    float* acc4 = accB;            // 2x5120
    float* acc3 = accB + 10240;    // 2x1280
    float* acc2 = accB + 12800;    // 2x1232
    float* acc1 = accB + 15264;    // 2x1232
    float* acc0 = accB + 17728;    // 2x1229   (total 20,186 floats; 20,480 zeroed)

    const float* W4 = (const float*)d_in[1];  const float* b4 = (const float*)d_in[2];
    const float* g4 = (const float*)d_in[3];  const float* bb4 = (const float*)d_in[4];
    const float* hw4 = (const float*)d_in[5]; const float* hb4 = (const float*)d_in[6];
    const float* W3 = (const float*)d_in[7];  const float* b3 = (const float*)d_in[8];
    const float* g3 = (const float*)d_in[9];  const float* bb3 = (const float*)d_in[10];
    const float* hw3 = (const float*)d_in[11]; const float* hb3 = (const float*)d_in[12];
    const float* W2 = (const float*)d_in[13]; const float* b2 = (const float*)d_in[14];
    const float* g2 = (const float*)d_in[15]; const float* bb2 = (const float*)d_in[16];
    const float* hw2 = (const float*)d_in[17]; const float* hb2 = (const float*)d_in[18];
    const float* W1 = (const float*)d_in[19]; const float* b1 = (const float*)d_in[20];
    const float* g1 = (const float*)d_in[21]; const float* bb1 = (const float*)d_in[22];
    const float* hw1 = (const float*)d_in[23]; const float* hb1 = (const float*)d_in[24];
    const float* W0 = (const float*)d_in[25]; const float* b0_ = (const float*)d_in[26];
    const float* g0 = (const float*)d_in[27]; const float* bb0 = (const float*)d_in[28];
    const float* hw0 = (const float*)d_in[29]; const float* hb0 = (const float*)d_in[30];

    // 1: fused x pack + W4..W1 cvt + W0 rows>=512 cvt + acc zeroing
    pack_cvt<<<PACK_BLOCKS + CVT_BLOCKS + W0P1_BLOCKS, 256, 0, stream>>>(
        x, ain0, ain1, W4, W3, W2, W1, W0, wbt, accB);

    // 2: s4 stats (MFMA in-register) -> acc4
    s4_stats<<<1024, 256, 0, stream>>>(xg, wbt, b4, acc4);
    // 3: s4 act recompute (BN from acc4) + s3 GEMM: h3 -> bufB, stats -> acc3
    s4s3_fused<<<1024, 256, 0, stream>>>(xg, wbt, wbt + 163840, b4, acc4, g4, bb4,
                                         hw4, hb4, b3, bufB, acc3, out);

    // 4: s2 GEMM with on-the-fly act3 + s3 head + s2 stats
    s2_fused<<<dim3(1, 32, 16), 256, 0, stream>>>(bufB, xg, wbt + 409600, acc3,
                                                  g3, bb3, hw3, hb3, b2,
                                                  bufC, acc2, out);
    // 5: s2 BN+tanh -> act2 (ain1) + s2 head
    bn_tanh_head<<<BDIM * 16 / 4, 256, 0, stream>>>(bufC, acc2, g2, bb2, hw2, hb2,
                                                    ain1, out, 16, 77, 1232, 5376, 4, 1344, 320, 1232);

    // 6: s1 GEMM (T=4 I=1332 O=308 Kpad=1344 Npad=320 KS=2, WbT @882688)
    gemm_split<64><<<640, 256, 0, stream>>>(ain1, wbt + 882688, partial,
                                            5376, 1344, 1344, 320, 2, 1280, 5, 8);
    // 7: s1 reduce + W0 rows [0,512) cvt (one launch)
    reduce1_cvtw0<<<320 + 2688, 256, 0, stream>>>(partial, b1, bufC, acc1, W0, wbt);
    // 8: s1 BN+tanh -> act1 (ain0) + s1 head
    bn_tanh_head<<<BDIM * 4 / 4, 256, 0, stream>>>(bufC, acc1, g1, bb1, hw1, hb1,
                                                   ain0, out, 4, 308, 1232, 5376, 4, 0, 336, 1232);

    // 9: s0 GEMM (T=1 I=5328 O=1229 Kpad=5376 Npad=1280 KS=4)
    gemm_split<128><<<640, 256, 0, stream>>>(ain0, wbt, partial,
                                             5376, 0, 5376, 1280, 4, 1280, 10, 4);
    // 10: s0 reduce
    reduce_bias_stats<<<dim3(20, 16), 256, 0, stream>>>(partial, b0_, bufC, acc0,
                                                        1, 1229, 1280, 4, 1232, 1229);
    // 11: s0 BN+tanh+head
    bn_tanh_head<<<BDIM / 4, 256, 0, stream>>>(bufC, acc0, g0, bb0, hw0, hb0,
                                               nullptr, out, 1, 1229, 1232, 1232, 1, 0, 340, 1229);
}